// Round 4
// baseline (915.264 us; speedup 1.0000x reference)
//
#include <hip/hip_runtime.h>
#include <stdint.h>

#define N_NODES 50000
#define N_EDGES 1600000
#define IN_DIM  128
#define OUT_DIM 64
#define HEADS   4
#define HO      (HEADS*OUT_DIM)   // 256

// ---------- helpers ----------
__device__ __forceinline__ unsigned fenc(float f) {
    unsigned u = __float_as_uint(f);
    return (u & 0x80000000u) ? ~u : (u | 0x80000000u);
}
__device__ __forceinline__ float fdec(unsigned u) {
    return __uint_as_float((u & 0x80000000u) ? (u ^ 0x80000000u) : ~u);
}
__device__ __forceinline__ float lrelu(float v) {
    return v >= 0.f ? v : 0.01f * v;
}

// ---------- kernel A: h = x @ W (per head), plus per-node scores ----------
#define NPW 8            // nodes per wave
#define WPB 4            // waves per block
#define NPB (NPW*WPB)    // 32 nodes per block

__global__ __launch_bounds__(256) void k_gemm(
    const float* __restrict__ x, const float* __restrict__ W,
    const float* __restrict__ a,
    float* __restrict__ h, float* __restrict__ s_src, float* __restrict__ s_dst)
{
    __shared__ float xs[NPB][IN_DIM];   // 16 KB
    const int tid  = threadIdx.x;
    const int wave = tid >> 6;
    const int lane = tid & 63;
    const int node0 = blockIdx.x * NPB;

    {
        float4* xsv = (float4*)&xs[0][0];
        const int ROW4 = IN_DIM / 4;            // 32
        const int total4 = NPB * ROW4;          // 1024
        for (int i = tid; i < total4; i += 256) {
            int row  = i / ROW4;
            int node = node0 + row;
            float4 v = make_float4(0.f, 0.f, 0.f, 0.f);
            if (node < N_NODES)
                v = ((const float4*)x)[(size_t)node * ROW4 + (i % ROW4)];
            xsv[i] = v;
        }
    }
    __syncthreads();

    const int head = lane >> 4;          // 0..3
    const int og   = (lane & 15) * 4;    // 0..60
    const int wn0  = wave * NPW;

    float4 acc[NPW];
    #pragma unroll
    for (int i = 0; i < NPW; ++i) acc[i] = make_float4(0.f, 0.f, 0.f, 0.f);

    const float* wp = &W[(size_t)(head * IN_DIM) * OUT_DIM + og];
    #pragma unroll 4
    for (int k = 0; k < IN_DIM; ++k) {
        float4 w4 = *(const float4*)(wp + (size_t)k * OUT_DIM);
        #pragma unroll
        for (int i = 0; i < NPW; ++i) {
            float xv = xs[wn0 + i][k];
            acc[i].x = fmaf(xv, w4.x, acc[i].x);
            acc[i].y = fmaf(xv, w4.y, acc[i].y);
            acc[i].z = fmaf(xv, w4.z, acc[i].z);
            acc[i].w = fmaf(xv, w4.w, acc[i].w);
        }
    }

    const float4 as = *(const float4*)&a[head * (2*OUT_DIM) + og];
    const float4 ad = *(const float4*)&a[head * (2*OUT_DIM) + OUT_DIM + og];

    #pragma unroll
    for (int i = 0; i < NPW; ++i) {
        int node = node0 + wn0 + i;
        if (node >= N_NODES) continue;
        *(float4*)&h[(size_t)node * HO + head * OUT_DIM + og] = acc[i];
        float ps = acc[i].x*as.x + acc[i].y*as.y + acc[i].z*as.z + acc[i].w*as.w;
        float pd = acc[i].x*ad.x + acc[i].y*ad.y + acc[i].z*ad.z + acc[i].w*ad.w;
        #pragma unroll
        for (int m = 8; m >= 1; m >>= 1) {
            ps += __shfl_xor(ps, m, 16);
            pd += __shfl_xor(pd, m, 16);
        }
        if ((lane & 15) == 0) {
            s_src[node * HEADS + head] = ps;
            s_dst[node * HEADS + head] = pd;
        }
    }
}

// ---------- kernel B: per-head global max + dst histogram ----------
__global__ __launch_bounds__(256) void k_max_hist(
    const int* __restrict__ esrc, const int* __restrict__ edst,
    const float* __restrict__ s_src, const float* __restrict__ s_dst,
    unsigned* __restrict__ gmax, int* __restrict__ cnt)
{
    float m0 = -1e30f, m1 = -1e30f, m2 = -1e30f, m3 = -1e30f;
    const int stride = gridDim.x * blockDim.x;
    for (int e = blockIdx.x * blockDim.x + threadIdx.x; e < N_EDGES; e += stride) {
        int s = esrc[e], d = edst[e];
        atomicAdd(&cnt[d], 1);
        float4 ss = *(const float4*)&s_src[s * HEADS];
        float4 sd = *(const float4*)&s_dst[d * HEADS];
        m0 = fmaxf(m0, lrelu(ss.x + sd.x));
        m1 = fmaxf(m1, lrelu(ss.y + sd.y));
        m2 = fmaxf(m2, lrelu(ss.z + sd.z));
        m3 = fmaxf(m3, lrelu(ss.w + sd.w));
    }
    #pragma unroll
    for (int m = 32; m >= 1; m >>= 1) {
        m0 = fmaxf(m0, __shfl_xor(m0, m));
        m1 = fmaxf(m1, __shfl_xor(m1, m));
        m2 = fmaxf(m2, __shfl_xor(m2, m));
        m3 = fmaxf(m3, __shfl_xor(m3, m));
    }
    if ((threadIdx.x & 63) == 0) {
        atomicMax(&gmax[0], fenc(m0));
        atomicMax(&gmax[1], fenc(m1));
        atomicMax(&gmax[2], fenc(m2));
        atomicMax(&gmax[3], fenc(m3));
    }
}

// ---------- kernel C: one-block exclusive scan of cnt -> row_start; zero cnt ----------
__global__ __launch_bounds__(1024) void k_scan(
    int* __restrict__ cnt, int* __restrict__ row_start)
{
    __shared__ int part[1024];
    const int t  = threadIdx.x;
    const int CH = (N_NODES + 1023) / 1024;      // 49
    const int lo = t * CH;
    const int hi = (lo + CH < N_NODES) ? lo + CH : N_NODES;

    int s = 0;
    for (int i = lo; i < hi; ++i) s += cnt[i];
    part[t] = s;
    __syncthreads();

    for (int off = 1; off < 1024; off <<= 1) {
        int v = (t >= off) ? part[t - off] : 0;
        __syncthreads();
        part[t] += v;
        __syncthreads();
    }

    int run = (t == 0) ? 0 : part[t - 1];
    for (int i = lo; i < hi; ++i) {
        row_start[i] = run;
        run += cnt[i];
        cnt[i] = 0;                               // becomes bucket cursor
    }
    if (t == 1023) row_start[N_NODES] = part[1023];
}

// ---------- kernel D: per-head sum of exp + bucket src ids by dst ----------
__global__ __launch_bounds__(256) void k_sum_bucket(
    const int* __restrict__ esrc, const int* __restrict__ edst,
    const float* __restrict__ s_src, const float* __restrict__ s_dst,
    const unsigned* __restrict__ gmax, double* __restrict__ gsum,
    const int* __restrict__ row_start, int* __restrict__ cursor,
    int* __restrict__ sorted_src)
{
    const float mx0 = fdec(gmax[0]);
    const float mx1 = fdec(gmax[1]);
    const float mx2 = fdec(gmax[2]);
    const float mx3 = fdec(gmax[3]);
    double a0 = 0.0, a1 = 0.0, a2 = 0.0, a3 = 0.0;
    const int stride = gridDim.x * blockDim.x;
    for (int e = blockIdx.x * blockDim.x + threadIdx.x; e < N_EDGES; e += stride) {
        int s = esrc[e], d = edst[e];
        int pos = row_start[d] + atomicAdd(&cursor[d], 1);
        sorted_src[pos] = s;
        float4 ss = *(const float4*)&s_src[s * HEADS];
        float4 sd = *(const float4*)&s_dst[d * HEADS];
        a0 += (double)expf(lrelu(ss.x + sd.x) - mx0);
        a1 += (double)expf(lrelu(ss.y + sd.y) - mx1);
        a2 += (double)expf(lrelu(ss.z + sd.z) - mx2);
        a3 += (double)expf(lrelu(ss.w + sd.w) - mx3);
    }
    #pragma unroll
    for (int m = 32; m >= 1; m >>= 1) {
        a0 += __shfl_xor(a0, m);
        a1 += __shfl_xor(a1, m);
        a2 += __shfl_xor(a2, m);
        a3 += __shfl_xor(a3, m);
    }
    if ((threadIdx.x & 63) == 0) {
        atomicAdd(&gsum[0], a0);
        atomicAdd(&gsum[1], a1);
        atomicAdd(&gsum[2], a2);
        atomicAdd(&gsum[3], a3);
    }
}

// ---------- kernel E: one wave per dst node, gather-reduce, no atomics ----------
__global__ __launch_bounds__(256) void k_agg(
    const int* __restrict__ row_start, const int* __restrict__ sorted_src,
    const float* __restrict__ h,
    const float* __restrict__ s_src, const float* __restrict__ s_dst,
    const unsigned* __restrict__ gmax, const double* __restrict__ gsum,
    float* __restrict__ out)
{
    const int wid = (int)((blockIdx.x * 256u + threadIdx.x) >> 6);   // node id
    if (wid >= N_NODES) return;
    const int lane = threadIdx.x & 63;
    const int head = lane >> 4;
    const int og   = (lane & 15) * 4;

    const int beg = row_start[wid];
    const int end = row_start[wid + 1];
    const float mx  = fdec(gmax[head]);
    const float inv = (float)(1.0 / gsum[head]);
    const float sd  = s_dst[wid * HEADS + head];

    float4 acc = make_float4(0.f, 0.f, 0.f, 0.f);

    int j = beg;
    for (; j + 1 < end; j += 2) {
        int s0 = sorted_src[j];
        int s1 = sorted_src[j + 1];
        float p0 = expf(lrelu(s_src[s0 * HEADS + head] + sd) - mx) * inv;
        float p1 = expf(lrelu(s_src[s1 * HEADS + head] + sd) - mx) * inv;
        float4 h0 = *(const float4*)&h[(size_t)s0 * HO + head * OUT_DIM + og];
        float4 h1 = *(const float4*)&h[(size_t)s1 * HO + head * OUT_DIM + og];
        acc.x = fmaf(p0, h0.x, acc.x); acc.y = fmaf(p0, h0.y, acc.y);
        acc.z = fmaf(p0, h0.z, acc.z); acc.w = fmaf(p0, h0.w, acc.w);
        acc.x = fmaf(p1, h1.x, acc.x); acc.y = fmaf(p1, h1.y, acc.y);
        acc.z = fmaf(p1, h1.z, acc.z); acc.w = fmaf(p1, h1.w, acc.w);
    }
    if (j < end) {
        int s0 = sorted_src[j];
        float p0 = expf(lrelu(s_src[s0 * HEADS + head] + sd) - mx) * inv;
        float4 h0 = *(const float4*)&h[(size_t)s0 * HO + head * OUT_DIM + og];
        acc.x = fmaf(p0, h0.x, acc.x); acc.y = fmaf(p0, h0.y, acc.y);
        acc.z = fmaf(p0, h0.z, acc.z); acc.w = fmaf(p0, h0.w, acc.w);
    }

    *(float4*)&out[(size_t)wid * HO + head * OUT_DIM + og] = acc;
}

// ---------- launch ----------
extern "C" void kernel_launch(void* const* d_in, const int* in_sizes, int n_in,
                              void* d_out, int out_size, void* d_ws, size_t ws_size,
                              hipStream_t stream)
{
    const float* x    = (const float*)d_in[0];
    const int*   eidx = (const int*)d_in[1];   // jax x64 off: int64 -> int32
    const float* W    = (const float*)d_in[2];
    const float* a    = (const float*)d_in[3];
    float* out = (float*)d_out;

    // workspace layout (bytes from d_ws base; base assumed >=8B aligned)
    float*    h      = (float*)d_ws;                                  // 12.8M floats
    float*    s_src  = h + (size_t)N_NODES * HO;                      // 200K floats
    float*    s_dst  = s_src + (size_t)N_NODES * HEADS;               // 200K floats
    double*   gsum   = (double*)(s_dst + (size_t)N_NODES * HEADS);    // 4 doubles (8B-aligned)
    unsigned* gmax   = (unsigned*)(gsum + 4);                         // 4 uints
    int*      row_start = (int*)(gmax + 4);                           // N_NODES+1 ints
    int*      cnt    = row_start + (N_NODES + 1);                     // N_NODES ints (hist/cursor)
    int*      sorted_src = cnt + N_NODES;                             // N_EDGES ints

    const int* esrc = eidx;
    const int* edst = eidx + N_EDGES;

    // zero: gsum(32B) + gmax(16B) contiguous; cnt
    hipMemsetAsync(gsum, 0, 4 * sizeof(double) + 4 * sizeof(unsigned), stream);
    hipMemsetAsync(cnt, 0, N_NODES * sizeof(int), stream);

    k_gemm<<<(N_NODES + NPB - 1) / NPB, 256, 0, stream>>>(x, W, a, h, s_src, s_dst);
    k_max_hist<<<1024, 256, 0, stream>>>(esrc, edst, s_src, s_dst, gmax, cnt);
    k_scan<<<1, 1024, 0, stream>>>(cnt, row_start);
    k_sum_bucket<<<1024, 256, 0, stream>>>(esrc, edst, s_src, s_dst, gmax, gsum,
                                           row_start, cnt, sorted_src);
    k_agg<<<(N_NODES * 64 + 255) / 256, 256, 0, stream>>>(row_start, sorted_src, h,
                                                          s_src, s_dst, gmax, gsum, out);
}

// Round 5
// 910.203 us; speedup vs baseline: 1.0056x; 1.0056x over previous
//
#include <hip/hip_runtime.h>
#include <stdint.h>

#define N_NODES 50000
#define N_EDGES 1600000
#define IN_DIM  128
#define OUT_DIM 64
#define HEADS   4
#define HO      (HEADS*OUT_DIM)   // 256

// ---------- helpers ----------
__device__ __forceinline__ unsigned fenc(float f) {
    unsigned u = __float_as_uint(f);
    return (u & 0x80000000u) ? ~u : (u | 0x80000000u);
}
__device__ __forceinline__ float fdec(unsigned u) {
    return __uint_as_float((u & 0x80000000u) ? (u ^ 0x80000000u) : ~u);
}
__device__ __forceinline__ float lrelu(float v) {
    return v >= 0.f ? v : 0.01f * v;
}

// ---------- kernel A: h = x @ W (per head), plus per-node scores ----------
#define NPW 8            // nodes per wave
#define WPB 4            // waves per block
#define NPB (NPW*WPB)    // 32 nodes per block

__global__ __launch_bounds__(256) void k_gemm(
    const float* __restrict__ x, const float* __restrict__ W,
    const float* __restrict__ a,
    float* __restrict__ h, float* __restrict__ s_src, float* __restrict__ s_dst)
{
    __shared__ float xs[NPB][IN_DIM];   // 16 KB
    const int tid  = threadIdx.x;
    const int wave = tid >> 6;
    const int lane = tid & 63;
    const int node0 = blockIdx.x * NPB;

    {
        float4* xsv = (float4*)&xs[0][0];
        const int ROW4 = IN_DIM / 4;            // 32
        const int total4 = NPB * ROW4;          // 1024
        for (int i = tid; i < total4; i += 256) {
            int row  = i / ROW4;
            int node = node0 + row;
            float4 v = make_float4(0.f, 0.f, 0.f, 0.f);
            if (node < N_NODES)
                v = ((const float4*)x)[(size_t)node * ROW4 + (i % ROW4)];
            xsv[i] = v;
        }
    }
    __syncthreads();

    const int head = lane >> 4;          // 0..3
    const int og   = (lane & 15) * 4;    // 0..60
    const int wn0  = wave * NPW;

    float4 acc[NPW];
    #pragma unroll
    for (int i = 0; i < NPW; ++i) acc[i] = make_float4(0.f, 0.f, 0.f, 0.f);

    const float* wp = &W[(size_t)(head * IN_DIM) * OUT_DIM + og];
    #pragma unroll 4
    for (int k = 0; k < IN_DIM; ++k) {
        float4 w4 = *(const float4*)(wp + (size_t)k * OUT_DIM);
        #pragma unroll
        for (int i = 0; i < NPW; ++i) {
            float xv = xs[wn0 + i][k];
            acc[i].x = fmaf(xv, w4.x, acc[i].x);
            acc[i].y = fmaf(xv, w4.y, acc[i].y);
            acc[i].z = fmaf(xv, w4.z, acc[i].z);
            acc[i].w = fmaf(xv, w4.w, acc[i].w);
        }
    }

    const float4 as = *(const float4*)&a[head * (2*OUT_DIM) + og];
    const float4 ad = *(const float4*)&a[head * (2*OUT_DIM) + OUT_DIM + og];

    #pragma unroll
    for (int i = 0; i < NPW; ++i) {
        int node = node0 + wn0 + i;
        if (node >= N_NODES) continue;
        *(float4*)&h[(size_t)node * HO + head * OUT_DIM + og] = acc[i];
        float ps = acc[i].x*as.x + acc[i].y*as.y + acc[i].z*as.z + acc[i].w*as.w;
        float pd = acc[i].x*ad.x + acc[i].y*ad.y + acc[i].z*ad.z + acc[i].w*ad.w;
        #pragma unroll
        for (int m = 8; m >= 1; m >>= 1) {
            ps += __shfl_xor(ps, m, 16);
            pd += __shfl_xor(pd, m, 16);
        }
        if ((lane & 15) == 0) {
            s_src[node * HEADS + head] = ps;
            s_dst[node * HEADS + head] = pd;
        }
    }
}

// ---------- kernel B: per-head global max + dst histogram ----------
__global__ __launch_bounds__(256) void k_max_hist(
    const int* __restrict__ esrc, const int* __restrict__ edst,
    const float* __restrict__ s_src, const float* __restrict__ s_dst,
    unsigned* __restrict__ gmax, int* __restrict__ cnt)
{
    float m0 = -1e30f, m1 = -1e30f, m2 = -1e30f, m3 = -1e30f;
    const int stride = gridDim.x * blockDim.x;
    for (int e = blockIdx.x * blockDim.x + threadIdx.x; e < N_EDGES; e += stride) {
        int s = esrc[e], d = edst[e];
        atomicAdd(&cnt[d], 1);
        float4 ss = *(const float4*)&s_src[s * HEADS];
        float4 sd = *(const float4*)&s_dst[d * HEADS];
        m0 = fmaxf(m0, lrelu(ss.x + sd.x));
        m1 = fmaxf(m1, lrelu(ss.y + sd.y));
        m2 = fmaxf(m2, lrelu(ss.z + sd.z));
        m3 = fmaxf(m3, lrelu(ss.w + sd.w));
    }
    #pragma unroll
    for (int m = 32; m >= 1; m >>= 1) {
        m0 = fmaxf(m0, __shfl_xor(m0, m));
        m1 = fmaxf(m1, __shfl_xor(m1, m));
        m2 = fmaxf(m2, __shfl_xor(m2, m));
        m3 = fmaxf(m3, __shfl_xor(m3, m));
    }
    if ((threadIdx.x & 63) == 0) {
        atomicMax(&gmax[0], fenc(m0));
        atomicMax(&gmax[1], fenc(m1));
        atomicMax(&gmax[2], fenc(m2));
        atomicMax(&gmax[3], fenc(m3));
    }
}

// ---------- kernel C: one-block exclusive scan of cnt -> row_start; zero cnt ----------
__global__ __launch_bounds__(1024) void k_scan(
    int* __restrict__ cnt, int* __restrict__ row_start)
{
    __shared__ int part[1024];
    const int t  = threadIdx.x;
    const int CH = (N_NODES + 1023) / 1024;      // 49
    const int lo = t * CH;
    const int hi = (lo + CH < N_NODES) ? lo + CH : N_NODES;

    int s = 0;
    for (int i = lo; i < hi; ++i) s += cnt[i];
    part[t] = s;
    __syncthreads();

    for (int off = 1; off < 1024; off <<= 1) {
        int v = (t >= off) ? part[t - off] : 0;
        __syncthreads();
        part[t] += v;
        __syncthreads();
    }

    int run = (t == 0) ? 0 : part[t - 1];
    for (int i = lo; i < hi; ++i) {
        row_start[i] = run;
        run += cnt[i];
        cnt[i] = 0;                               // becomes bucket cursor
    }
    if (t == 1023) row_start[N_NODES] = part[1023];
}

// ---------- kernel D: per-head sum of exp + bucket src ids by dst ----------
__global__ __launch_bounds__(256) void k_sum_bucket(
    const int* __restrict__ esrc, const int* __restrict__ edst,
    const float* __restrict__ s_src, const float* __restrict__ s_dst,
    const unsigned* __restrict__ gmax, double* __restrict__ gsum,
    const int* __restrict__ row_start, int* __restrict__ cursor,
    int* __restrict__ sorted_src)
{
    const float mx0 = fdec(gmax[0]);
    const float mx1 = fdec(gmax[1]);
    const float mx2 = fdec(gmax[2]);
    const float mx3 = fdec(gmax[3]);
    double a0 = 0.0, a1 = 0.0, a2 = 0.0, a3 = 0.0;
    const int stride = gridDim.x * blockDim.x;
    for (int e = blockIdx.x * blockDim.x + threadIdx.x; e < N_EDGES; e += stride) {
        int s = esrc[e], d = edst[e];
        int pos = row_start[d] + atomicAdd(&cursor[d], 1);
        sorted_src[pos] = s;
        float4 ss = *(const float4*)&s_src[s * HEADS];
        float4 sd = *(const float4*)&s_dst[d * HEADS];
        a0 += (double)expf(lrelu(ss.x + sd.x) - mx0);
        a1 += (double)expf(lrelu(ss.y + sd.y) - mx1);
        a2 += (double)expf(lrelu(ss.z + sd.z) - mx2);
        a3 += (double)expf(lrelu(ss.w + sd.w) - mx3);
    }
    #pragma unroll
    for (int m = 32; m >= 1; m >>= 1) {
        a0 += __shfl_xor(a0, m);
        a1 += __shfl_xor(a1, m);
        a2 += __shfl_xor(a2, m);
        a3 += __shfl_xor(a3, m);
    }
    if ((threadIdx.x & 63) == 0) {
        atomicAdd(&gsum[0], a0);
        atomicAdd(&gsum[1], a1);
        atomicAdd(&gsum[2], a2);
        atomicAdd(&gsum[3], a3);
    }
}

// ---------- kernel E: one wave per dst node, gather-reduce, no atomics ----------
__global__ __launch_bounds__(256) void k_agg(
    const int* __restrict__ row_start, const int* __restrict__ sorted_src,
    const float* __restrict__ h,
    const float* __restrict__ s_src, const float* __restrict__ s_dst,
    const unsigned* __restrict__ gmax, const double* __restrict__ gsum,
    float* __restrict__ out)
{
    const int wid = (int)((blockIdx.x * 256u + threadIdx.x) >> 6);   // node id
    if (wid >= N_NODES) return;
    const int lane = threadIdx.x & 63;
    const int head = lane >> 4;
    const int og   = (lane & 15) * 4;

    const int beg = row_start[wid];
    const int end = row_start[wid + 1];
    const float mx  = fdec(gmax[head]);
    const float inv = (float)(1.0 / gsum[head]);
    const float sd  = s_dst[wid * HEADS + head];

    float4 acc = make_float4(0.f, 0.f, 0.f, 0.f);

    int j = beg;
    for (; j + 1 < end; j += 2) {
        int s0 = sorted_src[j];
        int s1 = sorted_src[j + 1];
        float p0 = expf(lrelu(s_src[s0 * HEADS + head] + sd) - mx) * inv;
        float p1 = expf(lrelu(s_src[s1 * HEADS + head] + sd) - mx) * inv;
        float4 h0 = *(const float4*)&h[(size_t)s0 * HO + head * OUT_DIM + og];
        float4 h1 = *(const float4*)&h[(size_t)s1 * HO + head * OUT_DIM + og];
        acc.x = fmaf(p0, h0.x, acc.x); acc.y = fmaf(p0, h0.y, acc.y);
        acc.z = fmaf(p0, h0.z, acc.z); acc.w = fmaf(p0, h0.w, acc.w);
        acc.x = fmaf(p1, h1.x, acc.x); acc.y = fmaf(p1, h1.y, acc.y);
        acc.z = fmaf(p1, h1.z, acc.z); acc.w = fmaf(p1, h1.w, acc.w);
    }
    if (j < end) {
        int s0 = sorted_src[j];
        float p0 = expf(lrelu(s_src[s0 * HEADS + head] + sd) - mx) * inv;
        float4 h0 = *(const float4*)&h[(size_t)s0 * HO + head * OUT_DIM + og];
        acc.x = fmaf(p0, h0.x, acc.x); acc.y = fmaf(p0, h0.y, acc.y);
        acc.z = fmaf(p0, h0.z, acc.z); acc.w = fmaf(p0, h0.w, acc.w);
    }

    *(float4*)&out[(size_t)wid * HO + head * OUT_DIM + og] = acc;
}

// ---------- launch ----------
extern "C" void kernel_launch(void* const* d_in, const int* in_sizes, int n_in,
                              void* d_out, int out_size, void* d_ws, size_t ws_size,
                              hipStream_t stream)
{
    const float* x    = (const float*)d_in[0];
    const int*   eidx = (const int*)d_in[1];   // jax x64 off: int64 -> int32
    const float* W    = (const float*)d_in[2];
    const float* a    = (const float*)d_in[3];
    float* out = (float*)d_out;

    // workspace layout (bytes from d_ws base; base assumed >=8B aligned)
    float*    h      = (float*)d_ws;                                  // 12.8M floats
    float*    s_src  = h + (size_t)N_NODES * HO;                      // 200K floats
    float*    s_dst  = s_src + (size_t)N_NODES * HEADS;               // 200K floats
    double*   gsum   = (double*)(s_dst + (size_t)N_NODES * HEADS);    // 4 doubles (8B-aligned)
    unsigned* gmax   = (unsigned*)(gsum + 4);                         // 4 uints
    int*      row_start = (int*)(gmax + 4);                           // N_NODES+1 ints
    int*      cnt    = row_start + (N_NODES + 1);                     // N_NODES ints (hist/cursor)
    int*      sorted_src = cnt + N_NODES;                             // N_EDGES ints

    const int* esrc = eidx;
    const int* edst = eidx + N_EDGES;

    // zero: gsum(32B) + gmax(16B) contiguous; cnt
    hipMemsetAsync(gsum, 0, 4 * sizeof(double) + 4 * sizeof(unsigned), stream);
    hipMemsetAsync(cnt, 0, N_NODES * sizeof(int), stream);

    k_gemm<<<(N_NODES + NPB - 1) / NPB, 256, 0, stream>>>(x, W, a, h, s_src, s_dst);
    k_max_hist<<<1024, 256, 0, stream>>>(esrc, edst, s_src, s_dst, gmax, cnt);
    k_scan<<<1, 1024, 0, stream>>>(cnt, row_start);
    k_sum_bucket<<<1024, 256, 0, stream>>>(esrc, edst, s_src, s_dst, gmax, gsum,
                                           row_start, cnt, sorted_src);
    k_agg<<<(N_NODES * 64 + 255) / 256, 256, 0, stream>>>(row_start, sorted_src, h,
                                                          s_src, s_dst, gmax, gsum, out);
}

// Round 6
// 525.334 us; speedup vs baseline: 1.7423x; 1.7326x over previous
//
#include <hip/hip_runtime.h>
#include <stdint.h>

#define N_NODES 50000
#define N_EDGES 1600000
#define IN_DIM  128
#define OUT_DIM 64
#define HEADS   4
#define HO      (HEADS*OUT_DIM)   // 256

// ---------- helpers ----------
__device__ __forceinline__ unsigned fenc(float f) {
    unsigned u = __float_as_uint(f);
    return (u & 0x80000000u) ? ~u : (u | 0x80000000u);
}
__device__ __forceinline__ float fdec(unsigned u) {
    return __uint_as_float((u & 0x80000000u) ? (u ^ 0x80000000u) : ~u);
}
__device__ __forceinline__ float lrelu(float v) {
    return v >= 0.f ? v : 0.01f * v;
}

// ---------- kernel 1: fused  [h = x@W + per-node scores]  //  [dst hist + edge rank] ----------
#define NPW 8            // nodes per wave
#define WPB 4            // waves per block
#define NPB (NPW*WPB)    // 32 nodes per block
#define GEMM_BLOCKS ((N_NODES + NPB - 1) / NPB)   // 1563
#define HIST_BLOCKS 1024

__global__ __launch_bounds__(256) void k_gemm_hist(
    const float* __restrict__ x, const float* __restrict__ W,
    const float* __restrict__ a,
    float* __restrict__ h, float* __restrict__ s_src, float* __restrict__ s_dst,
    const int* __restrict__ edst, int* __restrict__ cnt, int* __restrict__ rank)
{
    if (blockIdx.x < HIST_BLOCKS) {
        // ---- histogram + rank branch (latency-bound; overlaps gemm blocks) ----
        const int stride = HIST_BLOCKS * 256;
        for (int e = blockIdx.x * 256 + threadIdx.x; e < N_EDGES; e += stride)
            rank[e] = atomicAdd(&cnt[edst[e]], 1);
        return;
    }

    // ---- gemm branch ----
    __shared__ float xs[NPB][IN_DIM];   // 16 KB
    const int tid  = threadIdx.x;
    const int wave = tid >> 6;
    const int lane = tid & 63;
    const int node0 = (blockIdx.x - HIST_BLOCKS) * NPB;

    {
        float4* xsv = (float4*)&xs[0][0];
        const int ROW4 = IN_DIM / 4;            // 32
        const int total4 = NPB * ROW4;          // 1024
        for (int i = tid; i < total4; i += 256) {
            int row  = i / ROW4;
            int node = node0 + row;
            float4 v = make_float4(0.f, 0.f, 0.f, 0.f);
            if (node < N_NODES)
                v = ((const float4*)x)[(size_t)node * ROW4 + (i % ROW4)];
            xsv[i] = v;
        }
    }
    __syncthreads();

    const int head = lane >> 4;          // 0..3
    const int og   = (lane & 15) * 4;    // 0..60
    const int wn0  = wave * NPW;

    float4 acc[NPW];
    #pragma unroll
    for (int i = 0; i < NPW; ++i) acc[i] = make_float4(0.f, 0.f, 0.f, 0.f);

    const float* wp = &W[(size_t)(head * IN_DIM) * OUT_DIM + og];
    #pragma unroll 4
    for (int k = 0; k < IN_DIM; ++k) {
        float4 w4 = *(const float4*)(wp + (size_t)k * OUT_DIM);
        #pragma unroll
        for (int i = 0; i < NPW; ++i) {
            float xv = xs[wn0 + i][k];
            acc[i].x = fmaf(xv, w4.x, acc[i].x);
            acc[i].y = fmaf(xv, w4.y, acc[i].y);
            acc[i].z = fmaf(xv, w4.z, acc[i].z);
            acc[i].w = fmaf(xv, w4.w, acc[i].w);
        }
    }

    const float4 as = *(const float4*)&a[head * (2*OUT_DIM) + og];
    const float4 ad = *(const float4*)&a[head * (2*OUT_DIM) + OUT_DIM + og];

    #pragma unroll
    for (int i = 0; i < NPW; ++i) {
        int node = node0 + wn0 + i;
        if (node >= N_NODES) continue;
        *(float4*)&h[(size_t)node * HO + head * OUT_DIM + og] = acc[i];
        float ps = acc[i].x*as.x + acc[i].y*as.y + acc[i].z*as.z + acc[i].w*as.w;
        float pd = acc[i].x*ad.x + acc[i].y*ad.y + acc[i].z*ad.z + acc[i].w*ad.w;
        #pragma unroll
        for (int m = 8; m >= 1; m >>= 1) {
            ps += __shfl_xor(ps, m, 16);
            pd += __shfl_xor(pd, m, 16);
        }
        if ((lane & 15) == 0) {
            s_src[node * HEADS + head] = ps;
            s_dst[node * HEADS + head] = pd;
        }
    }
}

// ---------- kernel 2: one-block exclusive scan of cnt -> row_start ----------
__global__ __launch_bounds__(1024) void k_scan(
    const int* __restrict__ cnt, int* __restrict__ row_start)
{
    __shared__ int part[1024];
    const int t  = threadIdx.x;
    const int CH = (N_NODES + 1023) / 1024;      // 49
    const int lo = t * CH;
    const int hi = (lo + CH < N_NODES) ? lo + CH : N_NODES;

    int s = 0;
    for (int i = lo; i < hi; ++i) s += cnt[i];
    part[t] = s;
    __syncthreads();

    for (int off = 1; off < 1024; off <<= 1) {
        int v = (t >= off) ? part[t - off] : 0;
        __syncthreads();
        part[t] += v;
        __syncthreads();
    }

    int run = (t == 0) ? 0 : part[t - 1];
    for (int i = lo; i < hi; ++i) {
        row_start[i] = run;
        run += cnt[i];
    }
    if (t == 1023) row_start[N_NODES] = part[1023];
}

// ---------- kernel 3: per-head node-level max of s_src and s_dst (softmax shift bound) ----------
__global__ __launch_bounds__(256) void k_nodemax(
    const float* __restrict__ s_src, const float* __restrict__ s_dst,
    unsigned* __restrict__ gmax_src, unsigned* __restrict__ gmax_dst)
{
    float4 ms = make_float4(-1e30f, -1e30f, -1e30f, -1e30f);
    float4 md = ms;
    const int stride = gridDim.x * blockDim.x;
    for (int n = blockIdx.x * blockDim.x + threadIdx.x; n < N_NODES; n += stride) {
        float4 vs = ((const float4*)s_src)[n];
        float4 vd = ((const float4*)s_dst)[n];
        ms.x = fmaxf(ms.x, vs.x); ms.y = fmaxf(ms.y, vs.y);
        ms.z = fmaxf(ms.z, vs.z); ms.w = fmaxf(ms.w, vs.w);
        md.x = fmaxf(md.x, vd.x); md.y = fmaxf(md.y, vd.y);
        md.z = fmaxf(md.z, vd.z); md.w = fmaxf(md.w, vd.w);
    }
    #pragma unroll
    for (int m = 32; m >= 1; m >>= 1) {
        ms.x = fmaxf(ms.x, __shfl_xor(ms.x, m)); ms.y = fmaxf(ms.y, __shfl_xor(ms.y, m));
        ms.z = fmaxf(ms.z, __shfl_xor(ms.z, m)); ms.w = fmaxf(ms.w, __shfl_xor(ms.w, m));
        md.x = fmaxf(md.x, __shfl_xor(md.x, m)); md.y = fmaxf(md.y, __shfl_xor(md.y, m));
        md.z = fmaxf(md.z, __shfl_xor(md.z, m)); md.w = fmaxf(md.w, __shfl_xor(md.w, m));
    }
    if ((threadIdx.x & 63) == 0) {
        atomicMax(&gmax_src[0], fenc(ms.x)); atomicMax(&gmax_src[1], fenc(ms.y));
        atomicMax(&gmax_src[2], fenc(ms.z)); atomicMax(&gmax_src[3], fenc(ms.w));
        atomicMax(&gmax_dst[0], fenc(md.x)); atomicMax(&gmax_dst[1], fenc(md.y));
        atomicMax(&gmax_dst[2], fenc(md.z)); atomicMax(&gmax_dst[3], fenc(md.w));
    }
}

// ---------- kernel 4: atomic-free bucket: sorted_src[row_start[d]+rank[e]] = s ----------
__global__ __launch_bounds__(256) void k_bucket(
    const int* __restrict__ esrc, const int* __restrict__ edst,
    const int* __restrict__ rank, const int* __restrict__ row_start,
    int* __restrict__ sorted_src)
{
    const int stride = gridDim.x * blockDim.x;
    for (int e = blockIdx.x * blockDim.x + threadIdx.x; e < N_EDGES; e += stride) {
        int d = edst[e];
        sorted_src[row_start[d] + rank[e]] = esrc[e];
    }
}

// ---------- kernel 5: one wave per dst node; unnormalized gather-reduce + per-node exp-sum ----------
__global__ __launch_bounds__(256) void k_agg(
    const int* __restrict__ row_start, const int* __restrict__ sorted_src,
    const float* __restrict__ h,
    const float* __restrict__ s_src, const float* __restrict__ s_dst,
    const unsigned* __restrict__ gmax_src, const unsigned* __restrict__ gmax_dst,
    float* __restrict__ sums, float* __restrict__ out)
{
    const int wid = (int)((blockIdx.x * 256u + threadIdx.x) >> 6);   // node id
    if (wid >= N_NODES) return;
    const int lane = threadIdx.x & 63;
    const int head = lane >> 4;
    const int og   = (lane & 15) * 4;

    const int beg = row_start[wid];
    const int end = row_start[wid + 1];
    // upper bound on the global max edge score for this head (lrelu monotonic)
    const float mx = lrelu(fdec(gmax_src[head]) + fdec(gmax_dst[head]));
    const float sd = s_dst[wid * HEADS + head];

    float4 acc = make_float4(0.f, 0.f, 0.f, 0.f);
    float  sum_p = 0.f;

    int j = beg;
    for (; j + 1 < end; j += 2) {
        int s0 = sorted_src[j];
        int s1 = sorted_src[j + 1];
        float p0 = expf(lrelu(s_src[s0 * HEADS + head] + sd) - mx);
        float p1 = expf(lrelu(s_src[s1 * HEADS + head] + sd) - mx);
        float4 h0 = *(const float4*)&h[(size_t)s0 * HO + head * OUT_DIM + og];
        float4 h1 = *(const float4*)&h[(size_t)s1 * HO + head * OUT_DIM + og];
        sum_p += p0 + p1;
        acc.x = fmaf(p0, h0.x, acc.x); acc.y = fmaf(p0, h0.y, acc.y);
        acc.z = fmaf(p0, h0.z, acc.z); acc.w = fmaf(p0, h0.w, acc.w);
        acc.x = fmaf(p1, h1.x, acc.x); acc.y = fmaf(p1, h1.y, acc.y);
        acc.z = fmaf(p1, h1.z, acc.z); acc.w = fmaf(p1, h1.w, acc.w);
    }
    if (j < end) {
        int s0 = sorted_src[j];
        float p0 = expf(lrelu(s_src[s0 * HEADS + head] + sd) - mx);
        float4 h0 = *(const float4*)&h[(size_t)s0 * HO + head * OUT_DIM + og];
        sum_p += p0;
        acc.x = fmaf(p0, h0.x, acc.x); acc.y = fmaf(p0, h0.y, acc.y);
        acc.z = fmaf(p0, h0.z, acc.z); acc.w = fmaf(p0, h0.w, acc.w);
    }

    *(float4*)&out[(size_t)wid * HO + head * OUT_DIM + og] = acc;
    if ((lane & 15) == 0) sums[wid * HEADS + head] = sum_p;   // identical across the 16-group
}

// ---------- kernel 6: reduce per-node exp-sums -> 1/gsum per head ----------
__global__ __launch_bounds__(1024) void k_reduce(
    const float* __restrict__ sums, float* __restrict__ inv4)
{
    double a0 = 0.0, a1 = 0.0, a2 = 0.0, a3 = 0.0;
    for (int n = threadIdx.x; n < N_NODES; n += 1024) {
        float4 v = ((const float4*)sums)[n];
        a0 += v.x; a1 += v.y; a2 += v.z; a3 += v.w;
    }
    #pragma unroll
    for (int m = 32; m >= 1; m >>= 1) {
        a0 += __shfl_xor(a0, m); a1 += __shfl_xor(a1, m);
        a2 += __shfl_xor(a2, m); a3 += __shfl_xor(a3, m);
    }
    __shared__ double part[16][4];
    const int w = threadIdx.x >> 6;
    if ((threadIdx.x & 63) == 0) {
        part[w][0] = a0; part[w][1] = a1; part[w][2] = a2; part[w][3] = a3;
    }
    __syncthreads();
    if (threadIdx.x < 4) {
        double t = 0.0;
        #pragma unroll
        for (int k = 0; k < 16; ++k) t += part[k][threadIdx.x];
        inv4[threadIdx.x] = (float)(1.0 / t);
    }
}

// ---------- kernel 7: out *= 1/gsum[head] ----------
__global__ __launch_bounds__(256) void k_scale(
    float* __restrict__ out, const float* __restrict__ inv4)
{
    const int i4 = blockIdx.x * 256 + threadIdx.x;     // float4 index
    if (i4 >= (N_NODES * HO) / 4) return;
    const int head = (i4 >> 4) & 3;                    // 16 float4 per head-block
    const float inv = inv4[head];
    float4 v = ((float4*)out)[i4];
    v.x *= inv; v.y *= inv; v.z *= inv; v.w *= inv;
    ((float4*)out)[i4] = v;
}

// ---------- launch ----------
extern "C" void kernel_launch(void* const* d_in, const int* in_sizes, int n_in,
                              void* d_out, int out_size, void* d_ws, size_t ws_size,
                              hipStream_t stream)
{
    const float* x    = (const float*)d_in[0];
    const int*   eidx = (const int*)d_in[1];   // jax x64 off: int64 -> int32
    const float* W    = (const float*)d_in[2];
    const float* a    = (const float*)d_in[3];
    float* out = (float*)d_out;

    // workspace layout
    float*    h        = (float*)d_ws;                               // 12.8M floats
    float*    s_src    = h + (size_t)N_NODES * HO;                   // 200K floats
    float*    s_dst    = s_src + (size_t)N_NODES * HEADS;            // 200K floats
    float*    sums     = s_dst + (size_t)N_NODES * HEADS;            // 200K floats
    float*    inv4     = sums + (size_t)N_NODES * HEADS;             // 4 floats
    unsigned* gmax_src = (unsigned*)(inv4 + 4);                      // 4 uints
    unsigned* gmax_dst = gmax_src + 4;                               // 4 uints
    int*      row_start = (int*)(gmax_dst + 4);                      // N_NODES+1 ints
    int*      cnt      = row_start + (N_NODES + 1);                  // N_NODES ints
    int*      rank     = cnt + N_NODES;                              // N_EDGES ints
    int*      sorted_src = rank + N_EDGES;                           // N_EDGES ints

    const int* esrc = eidx;
    const int* edst = eidx + N_EDGES;

    hipMemsetAsync(gmax_src, 0, 8 * sizeof(unsigned), stream);       // gmax_src+gmax_dst
    hipMemsetAsync(cnt, 0, N_NODES * sizeof(int), stream);

    k_gemm_hist<<<HIST_BLOCKS + GEMM_BLOCKS, 256, 0, stream>>>(
        x, W, a, h, s_src, s_dst, edst, cnt, rank);
    k_scan<<<1, 1024, 0, stream>>>(cnt, row_start);
    k_nodemax<<<64, 256, 0, stream>>>(s_src, s_dst, gmax_src, gmax_dst);
    k_bucket<<<2048, 256, 0, stream>>>(esrc, edst, rank, row_start, sorted_src);
    k_agg<<<(N_NODES * 64 + 255) / 256, 256, 0, stream>>>(
        row_start, sorted_src, h, s_src, s_dst, gmax_src, gmax_dst, sums, out);
    k_reduce<<<1, 1024, 0, stream>>>(sums, inv4);
    k_scale<<<(N_NODES * HO / 4 + 255) / 256, 256, 0, stream>>>(out, inv4);
}

// Round 7
// 411.093 us; speedup vs baseline: 2.2264x; 1.2779x over previous
//
#include <hip/hip_runtime.h>
#include <stdint.h>

#define N_NODES 50000
#define N_EDGES 1600000
#define IN_DIM  128
#define OUT_DIM 64
#define HEADS   4
#define HO      (HEADS*OUT_DIM)   // 256

// ---------- helpers ----------
__device__ __forceinline__ unsigned fenc(float f) {
    unsigned u = __float_as_uint(f);
    return (u & 0x80000000u) ? ~u : (u | 0x80000000u);
}
__device__ __forceinline__ float fdec(unsigned u) {
    return __uint_as_float((u & 0x80000000u) ? (u ^ 0x80000000u) : ~u);
}
__device__ __forceinline__ float lrelu(float v) {
    return v >= 0.f ? v : 0.01f * v;
}
__device__ __forceinline__ unsigned short f2bf(float f) {          // round-to-nearest-even
    unsigned u = __float_as_uint(f);
    return (unsigned short)((u + 0x7FFFu + ((u >> 16) & 1u)) >> 16);
}
__device__ __forceinline__ float bf2f(unsigned short b) {
    return __uint_as_float(((unsigned)b) << 16);
}

// ---------- kernel 1: fused  [h = x@W (bf16 out) + per-node scores]  //  [dst hist + rank] ----------
#define NPW 8            // nodes per wave
#define WPB 4            // waves per block
#define NPB (NPW*WPB)    // 32 nodes per block
#define GEMM_BLOCKS ((N_NODES + NPB - 1) / NPB)   // 1563
#define HIST_BLOCKS 1024

__global__ __launch_bounds__(256) void k_gemm_hist(
    const float* __restrict__ x, const float* __restrict__ W,
    const float* __restrict__ a,
    unsigned short* __restrict__ hb, float* __restrict__ s_src, float* __restrict__ s_dst,
    const int* __restrict__ edst, int* __restrict__ cnt, int* __restrict__ rank)
{
    if (blockIdx.x < HIST_BLOCKS) {
        // ---- histogram + rank branch (latency-bound; overlaps gemm blocks) ----
        const int stride = HIST_BLOCKS * 256;
        for (int e = blockIdx.x * 256 + threadIdx.x; e < N_EDGES; e += stride)
            rank[e] = atomicAdd(&cnt[edst[e]], 1);
        return;
    }

    // ---- gemm branch ----
    __shared__ float xs[NPB][IN_DIM];   // 16 KB
    const int tid  = threadIdx.x;
    const int wave = tid >> 6;
    const int lane = tid & 63;
    const int node0 = (blockIdx.x - HIST_BLOCKS) * NPB;

    {
        float4* xsv = (float4*)&xs[0][0];
        const int ROW4 = IN_DIM / 4;            // 32
        const int total4 = NPB * ROW4;          // 1024
        for (int i = tid; i < total4; i += 256) {
            int row  = i / ROW4;
            int node = node0 + row;
            float4 v = make_float4(0.f, 0.f, 0.f, 0.f);
            if (node < N_NODES)
                v = ((const float4*)x)[(size_t)node * ROW4 + (i % ROW4)];
            xsv[i] = v;
        }
    }
    __syncthreads();

    const int head = lane >> 4;          // 0..3
    const int og   = (lane & 15) * 4;    // 0..60
    const int wn0  = wave * NPW;

    float4 acc[NPW];
    #pragma unroll
    for (int i = 0; i < NPW; ++i) acc[i] = make_float4(0.f, 0.f, 0.f, 0.f);

    const float* wp = &W[(size_t)(head * IN_DIM) * OUT_DIM + og];
    #pragma unroll 4
    for (int k = 0; k < IN_DIM; ++k) {
        float4 w4 = *(const float4*)(wp + (size_t)k * OUT_DIM);
        #pragma unroll
        for (int i = 0; i < NPW; ++i) {
            float xv = xs[wn0 + i][k];
            acc[i].x = fmaf(xv, w4.x, acc[i].x);
            acc[i].y = fmaf(xv, w4.y, acc[i].y);
            acc[i].z = fmaf(xv, w4.z, acc[i].z);
            acc[i].w = fmaf(xv, w4.w, acc[i].w);
        }
    }

    const float4 as = *(const float4*)&a[head * (2*OUT_DIM) + og];
    const float4 ad = *(const float4*)&a[head * (2*OUT_DIM) + OUT_DIM + og];

    #pragma unroll
    for (int i = 0; i < NPW; ++i) {
        int node = node0 + wn0 + i;
        if (node >= N_NODES) continue;
        ushort4 hv;
        hv.x = f2bf(acc[i].x); hv.y = f2bf(acc[i].y);
        hv.z = f2bf(acc[i].z); hv.w = f2bf(acc[i].w);
        *(ushort4*)&hb[(size_t)node * HO + head * OUT_DIM + og] = hv;
        float ps = acc[i].x*as.x + acc[i].y*as.y + acc[i].z*as.z + acc[i].w*as.w;
        float pd = acc[i].x*ad.x + acc[i].y*ad.y + acc[i].z*ad.z + acc[i].w*ad.w;
        #pragma unroll
        for (int m = 8; m >= 1; m >>= 1) {
            ps += __shfl_xor(ps, m, 16);
            pd += __shfl_xor(pd, m, 16);
        }
        if ((lane & 15) == 0) {
            s_src[node * HEADS + head] = ps;
            s_dst[node * HEADS + head] = pd;
        }
    }
}

// ---------- kernel 2: one-block exclusive scan of cnt -> row_start ----------
__global__ __launch_bounds__(1024) void k_scan(
    const int* __restrict__ cnt, int* __restrict__ row_start)
{
    __shared__ int part[1024];
    const int t  = threadIdx.x;
    const int CH = (N_NODES + 1023) / 1024;      // 49
    const int lo = t * CH;
    const int hi = (lo + CH < N_NODES) ? lo + CH : N_NODES;

    int s = 0;
    for (int i = lo; i < hi; ++i) s += cnt[i];
    part[t] = s;
    __syncthreads();

    for (int off = 1; off < 1024; off <<= 1) {
        int v = (t >= off) ? part[t - off] : 0;
        __syncthreads();
        part[t] += v;
        __syncthreads();
    }

    int run = (t == 0) ? 0 : part[t - 1];
    for (int i = lo; i < hi; ++i) {
        row_start[i] = run;
        run += cnt[i];
    }
    if (t == 1023) row_start[N_NODES] = part[1023];
}

// ---------- kernel 3: per-head node-level max of s_src and s_dst (softmax shift bound) ----------
__global__ __launch_bounds__(256) void k_nodemax(
    const float* __restrict__ s_src, const float* __restrict__ s_dst,
    unsigned* __restrict__ gmax_src, unsigned* __restrict__ gmax_dst)
{
    float4 ms = make_float4(-1e30f, -1e30f, -1e30f, -1e30f);
    float4 md = ms;
    const int stride = gridDim.x * blockDim.x;
    for (int n = blockIdx.x * blockDim.x + threadIdx.x; n < N_NODES; n += stride) {
        float4 vs = ((const float4*)s_src)[n];
        float4 vd = ((const float4*)s_dst)[n];
        ms.x = fmaxf(ms.x, vs.x); ms.y = fmaxf(ms.y, vs.y);
        ms.z = fmaxf(ms.z, vs.z); ms.w = fmaxf(ms.w, vs.w);
        md.x = fmaxf(md.x, vd.x); md.y = fmaxf(md.y, vd.y);
        md.z = fmaxf(md.z, vd.z); md.w = fmaxf(md.w, vd.w);
    }
    #pragma unroll
    for (int m = 32; m >= 1; m >>= 1) {
        ms.x = fmaxf(ms.x, __shfl_xor(ms.x, m)); ms.y = fmaxf(ms.y, __shfl_xor(ms.y, m));
        ms.z = fmaxf(ms.z, __shfl_xor(ms.z, m)); ms.w = fmaxf(ms.w, __shfl_xor(ms.w, m));
        md.x = fmaxf(md.x, __shfl_xor(md.x, m)); md.y = fmaxf(md.y, __shfl_xor(md.y, m));
        md.z = fmaxf(md.z, __shfl_xor(md.z, m)); md.w = fmaxf(md.w, __shfl_xor(md.w, m));
    }
    if ((threadIdx.x & 63) == 0) {
        atomicMax(&gmax_src[0], fenc(ms.x)); atomicMax(&gmax_src[1], fenc(ms.y));
        atomicMax(&gmax_src[2], fenc(ms.z)); atomicMax(&gmax_src[3], fenc(ms.w));
        atomicMax(&gmax_dst[0], fenc(md.x)); atomicMax(&gmax_dst[1], fenc(md.y));
        atomicMax(&gmax_dst[2], fenc(md.z)); atomicMax(&gmax_dst[3], fenc(md.w));
    }
}

// ---------- kernel 4: atomic-free bucket: sorted_src[row_start[d]+rank[e]] = s ----------
__global__ __launch_bounds__(256) void k_bucket(
    const int* __restrict__ esrc, const int* __restrict__ edst,
    const int* __restrict__ rank, const int* __restrict__ row_start,
    int* __restrict__ sorted_src)
{
    const int stride = gridDim.x * blockDim.x;
    for (int e = blockIdx.x * blockDim.x + threadIdx.x; e < N_EDGES; e += stride) {
        int d = edst[e];
        sorted_src[row_start[d] + rank[e]] = esrc[e];
    }
}

// ---------- kernel 5: one wave per dst node; unnormalized gather-reduce (bf16 h) ----------
__global__ __launch_bounds__(256) void k_agg(
    const int* __restrict__ row_start, const int* __restrict__ sorted_src,
    const unsigned short* __restrict__ hb,
    const float* __restrict__ s_src, const float* __restrict__ s_dst,
    const unsigned* __restrict__ gmax_src, const unsigned* __restrict__ gmax_dst,
    float* __restrict__ sums, float* __restrict__ out)
{
    const int wid = (int)((blockIdx.x * 256u + threadIdx.x) >> 6);   // node id
    if (wid >= N_NODES) return;
    const int lane = threadIdx.x & 63;
    const int head = lane >> 4;
    const int og   = (lane & 15) * 4;
    const int hoff = head * OUT_DIM + og;

    const int beg = row_start[wid];
    const int end = row_start[wid + 1];
    // upper bound on the global max edge score for this head (lrelu monotonic)
    const float mx = lrelu(fdec(gmax_src[head]) + fdec(gmax_dst[head]));
    const float sd = s_dst[wid * HEADS + head];

    float4 acc = make_float4(0.f, 0.f, 0.f, 0.f);
    float  sum_p = 0.f;

    int j = beg;
    for (; j + 3 < end; j += 4) {
        int s0 = sorted_src[j];
        int s1 = sorted_src[j + 1];
        int s2 = sorted_src[j + 2];
        int s3 = sorted_src[j + 3];
        float p0 = __expf(lrelu(s_src[s0 * HEADS + head] + sd) - mx);
        float p1 = __expf(lrelu(s_src[s1 * HEADS + head] + sd) - mx);
        float p2 = __expf(lrelu(s_src[s2 * HEADS + head] + sd) - mx);
        float p3 = __expf(lrelu(s_src[s3 * HEADS + head] + sd) - mx);
        ushort4 u0 = *(const ushort4*)&hb[(size_t)s0 * HO + hoff];
        ushort4 u1 = *(const ushort4*)&hb[(size_t)s1 * HO + hoff];
        ushort4 u2 = *(const ushort4*)&hb[(size_t)s2 * HO + hoff];
        ushort4 u3 = *(const ushort4*)&hb[(size_t)s3 * HO + hoff];
        sum_p += (p0 + p1) + (p2 + p3);
        acc.x = fmaf(p0, bf2f(u0.x), acc.x); acc.y = fmaf(p0, bf2f(u0.y), acc.y);
        acc.z = fmaf(p0, bf2f(u0.z), acc.z); acc.w = fmaf(p0, bf2f(u0.w), acc.w);
        acc.x = fmaf(p1, bf2f(u1.x), acc.x); acc.y = fmaf(p1, bf2f(u1.y), acc.y);
        acc.z = fmaf(p1, bf2f(u1.z), acc.z); acc.w = fmaf(p1, bf2f(u1.w), acc.w);
        acc.x = fmaf(p2, bf2f(u2.x), acc.x); acc.y = fmaf(p2, bf2f(u2.y), acc.y);
        acc.z = fmaf(p2, bf2f(u2.z), acc.z); acc.w = fmaf(p2, bf2f(u2.w), acc.w);
        acc.x = fmaf(p3, bf2f(u3.x), acc.x); acc.y = fmaf(p3, bf2f(u3.y), acc.y);
        acc.z = fmaf(p3, bf2f(u3.z), acc.z); acc.w = fmaf(p3, bf2f(u3.w), acc.w);
    }
    for (; j < end; ++j) {
        int s0 = sorted_src[j];
        float p0 = __expf(lrelu(s_src[s0 * HEADS + head] + sd) - mx);
        ushort4 u0 = *(const ushort4*)&hb[(size_t)s0 * HO + hoff];
        sum_p += p0;
        acc.x = fmaf(p0, bf2f(u0.x), acc.x); acc.y = fmaf(p0, bf2f(u0.y), acc.y);
        acc.z = fmaf(p0, bf2f(u0.z), acc.z); acc.w = fmaf(p0, bf2f(u0.w), acc.w);
    }

    *(float4*)&out[(size_t)wid * HO + hoff] = acc;
    if ((lane & 15) == 0) sums[wid * HEADS + head] = sum_p;   // identical across the 16-group
}

// ---------- kernel 6: reduce per-node exp-sums -> 1/gsum per head ----------
__global__ __launch_bounds__(1024) void k_reduce(
    const float* __restrict__ sums, float* __restrict__ inv4)
{
    double a0 = 0.0, a1 = 0.0, a2 = 0.0, a3 = 0.0;
    for (int n = threadIdx.x; n < N_NODES; n += 1024) {
        float4 v = ((const float4*)sums)[n];
        a0 += v.x; a1 += v.y; a2 += v.z; a3 += v.w;
    }
    #pragma unroll
    for (int m = 32; m >= 1; m >>= 1) {
        a0 += __shfl_xor(a0, m); a1 += __shfl_xor(a1, m);
        a2 += __shfl_xor(a2, m); a3 += __shfl_xor(a3, m);
    }
    __shared__ double part[16][4];
    const int w = threadIdx.x >> 6;
    if ((threadIdx.x & 63) == 0) {
        part[w][0] = a0; part[w][1] = a1; part[w][2] = a2; part[w][3] = a3;
    }
    __syncthreads();
    if (threadIdx.x < 4) {
        double t = 0.0;
        #pragma unroll
        for (int k = 0; k < 16; ++k) t += part[k][threadIdx.x];
        inv4[threadIdx.x] = (float)(1.0 / t);
    }
}

// ---------- kernel 7: out *= 1/gsum[head] ----------
__global__ __launch_bounds__(256) void k_scale(
    float* __restrict__ out, const float* __restrict__ inv4)
{
    const int i4 = blockIdx.x * 256 + threadIdx.x;     // float4 index
    if (i4 >= (N_NODES * HO) / 4) return;
    const int head = (i4 >> 4) & 3;                    // 16 float4 per head-block
    const float inv = inv4[head];
    float4 v = ((float4*)out)[i4];
    v.x *= inv; v.y *= inv; v.z *= inv; v.w *= inv;
    ((float4*)out)[i4] = v;
}

// ---------- launch ----------
extern "C" void kernel_launch(void* const* d_in, const int* in_sizes, int n_in,
                              void* d_out, int out_size, void* d_ws, size_t ws_size,
                              hipStream_t stream)
{
    const float* x    = (const float*)d_in[0];
    const int*   eidx = (const int*)d_in[1];   // jax x64 off: int64 -> int32
    const float* W    = (const float*)d_in[2];
    const float* a    = (const float*)d_in[3];
    float* out = (float*)d_out;

    // workspace layout
    unsigned short* hb = (unsigned short*)d_ws;                      // 12.8M bf16 (25.6 MB)
    float*    s_src    = (float*)(hb + (size_t)N_NODES * HO);        // 200K floats
    float*    s_dst    = s_src + (size_t)N_NODES * HEADS;            // 200K floats
    float*    sums     = s_dst + (size_t)N_NODES * HEADS;            // 200K floats
    float*    inv4     = sums + (size_t)N_NODES * HEADS;             // 4 floats
    unsigned* gmax_src = (unsigned*)(inv4 + 4);                      // 4 uints
    unsigned* gmax_dst = gmax_src + 4;                               // 4 uints
    int*      row_start = (int*)(gmax_dst + 4);                      // N_NODES+1 ints
    int*      cnt      = row_start + (N_NODES + 1);                  // N_NODES ints
    int*      rank     = cnt + N_NODES;                              // N_EDGES ints
    int*      sorted_src = rank + N_EDGES;                           // N_EDGES ints

    const int* esrc = eidx;
    const int* edst = eidx + N_EDGES;

    hipMemsetAsync(gmax_src, 0, 8 * sizeof(unsigned), stream);       // gmax_src+gmax_dst
    hipMemsetAsync(cnt, 0, N_NODES * sizeof(int), stream);

    k_gemm_hist<<<HIST_BLOCKS + GEMM_BLOCKS, 256, 0, stream>>>(
        x, W, a, hb, s_src, s_dst, edst, cnt, rank);
    k_scan<<<1, 1024, 0, stream>>>(cnt, row_start);
    k_nodemax<<<64, 256, 0, stream>>>(s_src, s_dst, gmax_src, gmax_dst);
    k_bucket<<<2048, 256, 0, stream>>>(esrc, edst, rank, row_start, sorted_src);
    k_agg<<<(N_NODES * 64 + 255) / 256, 256, 0, stream>>>(
        row_start, sorted_src, hb, s_src, s_dst, gmax_src, gmax_dst, sums, out);
    k_reduce<<<1, 1024, 0, stream>>>(sums, inv4);
    k_scale<<<(N_NODES * HO / 4 + 255) / 256, 256, 0, stream>>>(out, inv4);
}

// Round 8
// 402.081 us; speedup vs baseline: 2.2763x; 1.0224x over previous
//
#include <hip/hip_runtime.h>
#include <stdint.h>

#define N_NODES 50000
#define N_EDGES 1600000
#define IN_DIM  128
#define OUT_DIM 64
#define HEADS   4
#define HO      (HEADS*OUT_DIM)   // 256

typedef __attribute__((ext_vector_type(8))) short short8;   // 8 bf16 (4 VGPR)
typedef __attribute__((ext_vector_type(4))) float f32x4;    // MFMA C/D

// ---------- helpers ----------
__device__ __forceinline__ unsigned fenc(float f) {
    unsigned u = __float_as_uint(f);
    return (u & 0x80000000u) ? ~u : (u | 0x80000000u);
}
__device__ __forceinline__ float fdec(unsigned u) {
    return __uint_as_float((u & 0x80000000u) ? (u ^ 0x80000000u) : ~u);
}
__device__ __forceinline__ float lrelu(float v) {
    return v >= 0.f ? v : 0.01f * v;
}
__device__ __forceinline__ unsigned short f2bf(float f) {          // RNE
    unsigned u = __float_as_uint(f);
    return (unsigned short)((u + 0x7FFFu + ((u >> 16) & 1u)) >> 16);
}
__device__ __forceinline__ float bf2f(unsigned short b) {
    return __uint_as_float(((unsigned)b) << 16);
}

// ---------- kernel 1: fused  [dst hist + rank] // [x -> bf16] // [W -> bf16 transposed] ----------
#define HIST_BLOCKS  1024
#define XCONV_BLOCKS 1024
#define WT_BLOCKS    32    // 256 n * 32 k4-chunks / 256 thr

__global__ __launch_bounds__(256) void k_prep_hist(
    const float* __restrict__ x, const float* __restrict__ W,
    const int* __restrict__ edst,
    unsigned short* __restrict__ xb, unsigned short* __restrict__ wt,
    int* __restrict__ cnt, int* __restrict__ rank)
{
    int b = blockIdx.x;
    if (b < HIST_BLOCKS) {
        const int stride = HIST_BLOCKS * 256;
        for (int e = b * 256 + threadIdx.x; e < N_EDGES; e += stride)
            rank[e] = atomicAdd(&cnt[edst[e]], 1);
        return;
    }
    b -= HIST_BLOCKS;
    if (b < XCONV_BLOCKS) {
        const int total4 = N_NODES * IN_DIM / 4;     // 1.6M float4
        const int stride = XCONV_BLOCKS * 256;
        for (int i = b * 256 + threadIdx.x; i < total4; i += stride) {
            float4 v = ((const float4*)x)[i];
            ushort4 u;
            u.x = f2bf(v.x); u.y = f2bf(v.y); u.z = f2bf(v.z); u.w = f2bf(v.w);
            ((ushort4*)xb)[i] = u;
        }
        return;
    }
    b -= XCONV_BLOCKS;
    // W[h][k][o] fp32 -> wt[n = h*64+o][k] bf16 (k-contiguous)
    {
        int item = b * 256 + threadIdx.x;            // [0, 8192)
        int n  = item >> 5;                          // 0..255
        int k0 = (item & 31) * 4;                    // 0..124
        int h = n >> 6, o = n & 63;
        const float* wp = &W[((size_t)h * IN_DIM + k0) * OUT_DIM + o];
        ushort4 u;
        u.x = f2bf(wp[0 * OUT_DIM]);
        u.y = f2bf(wp[1 * OUT_DIM]);
        u.z = f2bf(wp[2 * OUT_DIM]);
        u.w = f2bf(wp[3 * OUT_DIM]);
        *(ushort4*)&wt[(size_t)n * IN_DIM + k0] = u;
    }
}

// ---------- kernel 2: MFMA gemm  hb[64 rows/block][256] = xb @ wt^T ----------
// 4 waves/block, wave computes 16 rows x 256 cols, K=128 (4 ksteps of 32).
// LDS: A 16KB + B 64KB, XOR-swizzled (byte ^= ((row&7)<<4)) for conflict-free ds_read_b128.
#define BM 64
#define GEMM_BLOCKS ((N_NODES + BM - 1) / BM)   // 782

__global__ __launch_bounds__(256) void k_gemm(
    const unsigned short* __restrict__ xb, const unsigned short* __restrict__ wt,
    unsigned short* __restrict__ hb)
{
    extern __shared__ char smem[];               // 16384 (A) + 65536 (B)
    char* Alds = smem;
    char* Blds = smem + 16384;

    const int tid  = threadIdx.x;
    const int wave = tid >> 6;
    const int lane = tid & 63;
    const int node0 = blockIdx.x * BM;

    // ---- stage A (linear global -> swizzled LDS) ----
    {
        const char* xsrc = (const char*)xb + (size_t)node0 * 256;  // 64 rows x 256 B
        #pragma unroll
        for (int j = 0; j < 4; ++j) {
            int o = (j * 256 + tid) * 16;                          // [0,16384)
            uint4 v = *(const uint4*)(xsrc + o);                   // OOB rows read ws garbage; never stored
            int sw = o ^ (((o >> 8) & 7) << 4);
            *(uint4*)(Alds + sw) = v;
        }
    }
    // ---- stage B ----
    {
        const char* wsrc = (const char*)wt;                        // 256 n x 256 B
        #pragma unroll
        for (int j = 0; j < 16; ++j) {
            int o = (j * 256 + tid) * 16;                          // [0,65536)
            uint4 v = *(const uint4*)(wsrc + o);
            int sw = o ^ (((o >> 8) & 7) << 4);
            *(uint4*)(Blds + sw) = v;
        }
    }
    __syncthreads();

    const int wr0  = wave * 16;
    const int l15  = lane & 15;
    const int lhi  = lane >> 4;           // 0..3
    const int kxor = (lane & 7) << 4;     // swizzle const for this lane's row/col

    // A frags: row = wr0 + l15, k = s*32 + lhi*8  -> byte (row*256) + ((s*64 + lhi*16) ^ kxor)
    short8 af[4];
    #pragma unroll
    for (int s = 0; s < 4; ++s)
        af[s] = *(const short8*)(Alds + (wr0 + l15) * 256 + ((s * 64 + lhi * 16) ^ kxor));

    f32x4 acc[16];
    #pragma unroll
    for (int nt = 0; nt < 16; ++nt) acc[nt] = (f32x4){0.f, 0.f, 0.f, 0.f};

    #pragma unroll
    for (int nt = 0; nt < 16; ++nt) {
        const char* bbase = Blds + (nt * 16 + l15) * 256;
        #pragma unroll
        for (int s = 0; s < 4; ++s) {
            short8 bf = *(const short8*)(bbase + ((s * 64 + lhi * 16) ^ kxor));
            acc[nt] = __builtin_amdgcn_mfma_f32_16x16x32_bf16(af[s], bf, acc[nt], 0, 0, 0);
        }
    }

    // ---- epilogue: C/D col=lane&15, row=(lane>>4)*4+r  (m89-verified) ----
    #pragma unroll
    for (int nt = 0; nt < 16; ++nt) {
        int col = nt * 16 + l15;
        #pragma unroll
        for (int r = 0; r < 4; ++r) {
            int node = node0 + wr0 + lhi * 4 + r;
            if (node < N_NODES)
                hb[(size_t)node * HO + col] = f2bf(acc[nt][r]);
        }
    }
}

// ---------- kernel 3: per-(node,head) scores from bf16 h ----------
__global__ __launch_bounds__(256) void k_scores(
    const unsigned short* __restrict__ hb, const float* __restrict__ a,
    float* __restrict__ s_src, float* __restrict__ s_dst)
{
    int t = blockIdx.x * 256 + threadIdx.x;       // node*4 + head
    if (t >= N_NODES * HEADS) return;
    int node = t >> 2, head = t & 3;
    const unsigned short* hp = hb + (size_t)node * HO + head * OUT_DIM;
    const float* asrc = a + head * (2 * OUT_DIM);
    const float* adst = asrc + OUT_DIM;
    float ps = 0.f, pd = 0.f;
    #pragma unroll 4
    for (int o = 0; o < OUT_DIM; o += 4) {
        ushort4 u = *(const ushort4*)(hp + o);
        float h0 = bf2f(u.x), h1 = bf2f(u.y), h2 = bf2f(u.z), h3 = bf2f(u.w);
        float4 s4 = *(const float4*)(asrc + o);
        float4 d4 = *(const float4*)(adst + o);
        ps += h0 * s4.x + h1 * s4.y + h2 * s4.z + h3 * s4.w;
        pd += h0 * d4.x + h1 * d4.y + h2 * d4.z + h3 * d4.w;
    }
    s_src[t] = ps;
    s_dst[t] = pd;
}

// ---------- kernel 4: one-block exclusive scan of cnt -> row_start ----------
__global__ __launch_bounds__(1024) void k_scan(
    const int* __restrict__ cnt, int* __restrict__ row_start)
{
    __shared__ int part[1024];
    const int t  = threadIdx.x;
    const int CH = (N_NODES + 1023) / 1024;      // 49
    const int lo = t * CH;
    const int hi = (lo + CH < N_NODES) ? lo + CH : N_NODES;

    int s = 0;
    for (int i = lo; i < hi; ++i) s += cnt[i];
    part[t] = s;
    __syncthreads();

    for (int off = 1; off < 1024; off <<= 1) {
        int v = (t >= off) ? part[t - off] : 0;
        __syncthreads();
        part[t] += v;
        __syncthreads();
    }

    int run = (t == 0) ? 0 : part[t - 1];
    for (int i = lo; i < hi; ++i) {
        row_start[i] = run;
        run += cnt[i];
    }
    if (t == 1023) row_start[N_NODES] = part[1023];
}

// ---------- kernel 5: per-head node-level max of s_src / s_dst ----------
__global__ __launch_bounds__(256) void k_nodemax(
    const float* __restrict__ s_src, const float* __restrict__ s_dst,
    unsigned* __restrict__ gmax_src, unsigned* __restrict__ gmax_dst)
{
    float4 ms = make_float4(-1e30f, -1e30f, -1e30f, -1e30f);
    float4 md = ms;
    const int stride = gridDim.x * blockDim.x;
    for (int n = blockIdx.x * blockDim.x + threadIdx.x; n < N_NODES; n += stride) {
        float4 vs = ((const float4*)s_src)[n];
        float4 vd = ((const float4*)s_dst)[n];
        ms.x = fmaxf(ms.x, vs.x); ms.y = fmaxf(ms.y, vs.y);
        ms.z = fmaxf(ms.z, vs.z); ms.w = fmaxf(ms.w, vs.w);
        md.x = fmaxf(md.x, vd.x); md.y = fmaxf(md.y, vd.y);
        md.z = fmaxf(md.z, vd.z); md.w = fmaxf(md.w, vd.w);
    }
    #pragma unroll
    for (int m = 32; m >= 1; m >>= 1) {
        ms.x = fmaxf(ms.x, __shfl_xor(ms.x, m)); ms.y = fmaxf(ms.y, __shfl_xor(ms.y, m));
        ms.z = fmaxf(ms.z, __shfl_xor(ms.z, m)); ms.w = fmaxf(ms.w, __shfl_xor(ms.w, m));
        md.x = fmaxf(md.x, __shfl_xor(md.x, m)); md.y = fmaxf(md.y, __shfl_xor(md.y, m));
        md.z = fmaxf(md.z, __shfl_xor(md.z, m)); md.w = fmaxf(md.w, __shfl_xor(md.w, m));
    }
    if ((threadIdx.x & 63) == 0) {
        atomicMax(&gmax_src[0], fenc(ms.x)); atomicMax(&gmax_src[1], fenc(ms.y));
        atomicMax(&gmax_src[2], fenc(ms.z)); atomicMax(&gmax_src[3], fenc(ms.w));
        atomicMax(&gmax_dst[0], fenc(md.x)); atomicMax(&gmax_dst[1], fenc(md.y));
        atomicMax(&gmax_dst[2], fenc(md.z)); atomicMax(&gmax_dst[3], fenc(md.w));
    }
}

// ---------- kernel 6: atomic-free bucket ----------
__global__ __launch_bounds__(256) void k_bucket(
    const int* __restrict__ esrc, const int* __restrict__ edst,
    const int* __restrict__ rank, const int* __restrict__ row_start,
    int* __restrict__ sorted_src)
{
    const int stride = gridDim.x * blockDim.x;
    for (int e = blockIdx.x * blockDim.x + threadIdx.x; e < N_EDGES; e += stride) {
        int d = edst[e];
        sorted_src[row_start[d] + rank[e]] = esrc[e];
    }
}

// ---------- kernel 7: one wave per dst node; unnormalized gather-reduce (bf16 h) ----------
__global__ __launch_bounds__(256) void k_agg(
    const int* __restrict__ row_start, const int* __restrict__ sorted_src,
    const unsigned short* __restrict__ hb,
    const float* __restrict__ s_src, const float* __restrict__ s_dst,
    const unsigned* __restrict__ gmax_src, const unsigned* __restrict__ gmax_dst,
    float* __restrict__ sums, float* __restrict__ out)
{
    const int wid = (int)((blockIdx.x * 256u + threadIdx.x) >> 6);   // node id
    if (wid >= N_NODES) return;
    const int lane = threadIdx.x & 63;
    const int head = lane >> 4;
    const int og   = (lane & 15) * 4;
    const int hoff = head * OUT_DIM + og;

    const int beg = row_start[wid];
    const int end = row_start[wid + 1];
    const float mx = lrelu(fdec(gmax_src[head]) + fdec(gmax_dst[head]));
    const float sd = s_dst[wid * HEADS + head];

    float4 acc = make_float4(0.f, 0.f, 0.f, 0.f);
    float  sum_p = 0.f;

    int j = beg;
    for (; j + 3 < end; j += 4) {
        int s0 = sorted_src[j];
        int s1 = sorted_src[j + 1];
        int s2 = sorted_src[j + 2];
        int s3 = sorted_src[j + 3];
        float p0 = __expf(lrelu(s_src[s0 * HEADS + head] + sd) - mx);
        float p1 = __expf(lrelu(s_src[s1 * HEADS + head] + sd) - mx);
        float p2 = __expf(lrelu(s_src[s2 * HEADS + head] + sd) - mx);
        float p3 = __expf(lrelu(s_src[s3 * HEADS + head] + sd) - mx);
        ushort4 u0 = *(const ushort4*)&hb[(size_t)s0 * HO + hoff];
        ushort4 u1 = *(const ushort4*)&hb[(size_t)s1 * HO + hoff];
        ushort4 u2 = *(const ushort4*)&hb[(size_t)s2 * HO + hoff];
        ushort4 u3 = *(const ushort4*)&hb[(size_t)s3 * HO + hoff];
        sum_p += (p0 + p1) + (p2 + p3);
        acc.x = fmaf(p0, bf2f(u0.x), acc.x); acc.y = fmaf(p0, bf2f(u0.y), acc.y);
        acc.z = fmaf(p0, bf2f(u0.z), acc.z); acc.w = fmaf(p0, bf2f(u0.w), acc.w);
        acc.x = fmaf(p1, bf2f(u1.x), acc.x); acc.y = fmaf(p1, bf2f(u1.y), acc.y);
        acc.z = fmaf(p1, bf2f(u1.z), acc.z); acc.w = fmaf(p1, bf2f(u1.w), acc.w);
        acc.x = fmaf(p2, bf2f(u2.x), acc.x); acc.y = fmaf(p2, bf2f(u2.y), acc.y);
        acc.z = fmaf(p2, bf2f(u2.z), acc.z); acc.w = fmaf(p2, bf2f(u2.w), acc.w);
        acc.x = fmaf(p3, bf2f(u3.x), acc.x); acc.y = fmaf(p3, bf2f(u3.y), acc.y);
        acc.z = fmaf(p3, bf2f(u3.z), acc.z); acc.w = fmaf(p3, bf2f(u3.w), acc.w);
    }
    for (; j < end; ++j) {
        int s0 = sorted_src[j];
        float p0 = __expf(lrelu(s_src[s0 * HEADS + head] + sd) - mx);
        ushort4 u0 = *(const ushort4*)&hb[(size_t)s0 * HO + hoff];
        sum_p += p0;
        acc.x = fmaf(p0, bf2f(u0.x), acc.x); acc.y = fmaf(p0, bf2f(u0.y), acc.y);
        acc.z = fmaf(p0, bf2f(u0.z), acc.z); acc.w = fmaf(p0, bf2f(u0.w), acc.w);
    }

    *(float4*)&out[(size_t)wid * HO + hoff] = acc;
    if ((lane & 15) == 0) sums[wid * HEADS + head] = sum_p;
}

// ---------- kernel 8: reduce per-node exp-sums -> 1/gsum per head ----------
__global__ __launch_bounds__(1024) void k_reduce(
    const float* __restrict__ sums, float* __restrict__ inv4)
{
    double a0 = 0.0, a1 = 0.0, a2 = 0.0, a3 = 0.0;
    for (int n = threadIdx.x; n < N_NODES; n += 1024) {
        float4 v = ((const float4*)sums)[n];
        a0 += v.x; a1 += v.y; a2 += v.z; a3 += v.w;
    }
    #pragma unroll
    for (int m = 32; m >= 1; m >>= 1) {
        a0 += __shfl_xor(a0, m); a1 += __shfl_xor(a1, m);
        a2 += __shfl_xor(a2, m); a3 += __shfl_xor(a3, m);
    }
    __shared__ double part[16][4];
    const int w = threadIdx.x >> 6;
    if ((threadIdx.x & 63) == 0) {
        part[w][0] = a0; part[w][1] = a1; part[w][2] = a2; part[w][3] = a3;
    }
    __syncthreads();
    if (threadIdx.x < 4) {
        double t = 0.0;
        #pragma unroll
        for (int k = 0; k < 16; ++k) t += part[k][threadIdx.x];
        inv4[threadIdx.x] = (float)(1.0 / t);
    }
}

// ---------- kernel 9: out *= 1/gsum[head] ----------
__global__ __launch_bounds__(256) void k_scale(
    float* __restrict__ out, const float* __restrict__ inv4)
{
    const int i4 = blockIdx.x * 256 + threadIdx.x;     // float4 index
    if (i4 >= (N_NODES * HO) / 4) return;
    const int head = (i4 >> 4) & 3;
    const float inv = inv4[head];
    float4 v = ((float4*)out)[i4];
    v.x *= inv; v.y *= inv; v.z *= inv; v.w *= inv;
    ((float4*)out)[i4] = v;
}

// ---------- launch ----------
extern "C" void kernel_launch(void* const* d_in, const int* in_sizes, int n_in,
                              void* d_out, int out_size, void* d_ws, size_t ws_size,
                              hipStream_t stream)
{
    const float* x    = (const float*)d_in[0];
    const int*   eidx = (const int*)d_in[1];   // jax x64 off: int64 -> int32
    const float* W    = (const float*)d_in[2];
    const float* a    = (const float*)d_in[3];
    float* out = (float*)d_out;

    // workspace layout
    unsigned short* hb = (unsigned short*)d_ws;                      // 12.8M bf16
    unsigned short* xb = hb + (size_t)N_NODES * HO;                  // 6.4M bf16
    unsigned short* wt = xb + (size_t)N_NODES * IN_DIM;              // 32768 bf16
    float*    s_src    = (float*)(wt + (size_t)HO * IN_DIM);
    float*    s_dst    = s_src + (size_t)N_NODES * HEADS;
    float*    sums     = s_dst + (size_t)N_NODES * HEADS;
    float*    inv4     = sums + (size_t)N_NODES * HEADS;
    unsigned* gmax_src = (unsigned*)(inv4 + 4);
    unsigned* gmax_dst = gmax_src + 4;
    int*      row_start = (int*)(gmax_dst + 4);
    int*      cnt      = row_start + (N_NODES + 1);
    int*      rank     = cnt + N_NODES;
    int*      sorted_src = rank + N_EDGES;

    const int* esrc = eidx;
    const int* edst = eidx + N_EDGES;

    hipMemsetAsync(gmax_src, 0, 8 * sizeof(unsigned), stream);
    hipMemsetAsync(cnt, 0, N_NODES * sizeof(int), stream);

    k_prep_hist<<<HIST_BLOCKS + XCONV_BLOCKS + WT_BLOCKS, 256, 0, stream>>>(
        x, W, edst, xb, wt, cnt, rank);
    k_gemm<<<GEMM_BLOCKS, 256, 81920, stream>>>(xb, wt, hb);
    k_scores<<<(N_NODES * HEADS + 255) / 256, 256, 0, stream>>>(hb, a, s_src, s_dst);
    k_scan<<<1, 1024, 0, stream>>>(cnt, row_start);
    k_nodemax<<<64, 256, 0, stream>>>(s_src, s_dst, gmax_src, gmax_dst);
    k_bucket<<<2048, 256, 0, stream>>>(esrc, edst, rank, row_start, sorted_src);
    k_agg<<<(N_NODES * 64 + 255) / 256, 256, 0, stream>>>(
        row_start, sorted_src, hb, s_src, s_dst, gmax_src, gmax_dst, sums, out);
    k_reduce<<<1, 1024, 0, stream>>>(sums, inv4);
    k_scale<<<(N_NODES * HO / 4 + 255) / 256, 256, 0, stream>>>(out, inv4);
}

// Round 9
// 360.132 us; speedup vs baseline: 2.5415x; 1.1165x over previous
//
#include <hip/hip_runtime.h>
#include <stdint.h>

#define N_NODES 50000
#define N_EDGES 1600000
#define IN_DIM  128
#define OUT_DIM 64
#define HEADS   4
#define HO      (HEADS*OUT_DIM)   // 256

typedef __attribute__((ext_vector_type(8))) short short8;            // 8 bf16 (4 VGPR)
typedef __attribute__((ext_vector_type(8))) unsigned short bf16x8;   // 8 bf16 payload
typedef __attribute__((ext_vector_type(4))) float f32x4;             // MFMA C/D

// ---------- helpers ----------
__device__ __forceinline__ unsigned fenc(float f) {
    unsigned u = __float_as_uint(f);
    return (u & 0x80000000u) ? ~u : (u | 0x80000000u);
}
__device__ __forceinline__ float fdec(unsigned u) {
    return __uint_as_float((u & 0x80000000u) ? (u ^ 0x80000000u) : ~u);
}
__device__ __forceinline__ float lrelu(float v) {
    return v >= 0.f ? v : 0.01f * v;
}
__device__ __forceinline__ unsigned short f2bf(float f) {          // RNE
    unsigned u = __float_as_uint(f);
    return (unsigned short)((u + 0x7FFFu + ((u >> 16) & 1u)) >> 16);
}
__device__ __forceinline__ float bf2f(unsigned short b) {
    return __uint_as_float(((unsigned)b) << 16);
}

// ---------- kernel 1: fused  [dst hist + rank] // [x -> bf16] // [W -> bf16 transposed] ----------
#define HIST_BLOCKS  1024
#define XCONV_BLOCKS 1024
#define WT_BLOCKS    32    // 256 n * 32 k4-chunks / 256 thr

__global__ __launch_bounds__(256) void k_prep_hist(
    const float* __restrict__ x, const float* __restrict__ W,
    const int* __restrict__ edst,
    unsigned short* __restrict__ xb, unsigned short* __restrict__ wt,
    int* __restrict__ cnt, int* __restrict__ rank)
{
    int b = blockIdx.x;
    if (b < HIST_BLOCKS) {
        const int stride = HIST_BLOCKS * 256;
        for (int e = b * 256 + threadIdx.x; e < N_EDGES; e += stride)
            rank[e] = atomicAdd(&cnt[edst[e]], 1);
        return;
    }
    b -= HIST_BLOCKS;
    if (b < XCONV_BLOCKS) {
        const int total4 = N_NODES * IN_DIM / 4;     // 1.6M float4
        const int stride = XCONV_BLOCKS * 256;
        for (int i = b * 256 + threadIdx.x; i < total4; i += stride) {
            float4 v = ((const float4*)x)[i];
            ushort4 u;
            u.x = f2bf(v.x); u.y = f2bf(v.y); u.z = f2bf(v.z); u.w = f2bf(v.w);
            ((ushort4*)xb)[i] = u;
        }
        return;
    }
    b -= XCONV_BLOCKS;
    // W[h][k][o] fp32 -> wt[n = h*64+o][k] bf16 (k-contiguous)
    {
        int item = b * 256 + threadIdx.x;            // [0, 8192)
        int n  = item >> 5;                          // 0..255
        int k0 = (item & 31) * 4;                    // 0..124
        int h = n >> 6, o = n & 63;
        const float* wp = &W[((size_t)h * IN_DIM + k0) * OUT_DIM + o];
        ushort4 u;
        u.x = f2bf(wp[0 * OUT_DIM]);
        u.y = f2bf(wp[1 * OUT_DIM]);
        u.z = f2bf(wp[2 * OUT_DIM]);
        u.w = f2bf(wp[3 * OUT_DIM]);
        *(ushort4*)&wt[(size_t)n * IN_DIM + k0] = u;
    }
}

// ---------- kernel 2: MFMA gemm  hb = xb @ wt^T  + fused per-node scores ----------
// 4 waves/block, wave computes 16 rows x 256 cols, K=128 (4 ksteps of 32).
// LDS: A 16KB + B 64KB, XOR-swizzled (byte ^= ((row&7)<<4)) for conflict-free ds_read_b128.
#define BM 64
#define GEMM_BLOCKS ((N_NODES + BM - 1) / BM)   // 782

__global__ __launch_bounds__(256) void k_gemm(
    const unsigned short* __restrict__ xb, const unsigned short* __restrict__ wt,
    const float* __restrict__ a,
    unsigned short* __restrict__ hb, float* __restrict__ s_src, float* __restrict__ s_dst)
{
    extern __shared__ char smem[];               // 16384 (A) + 65536 (B)
    char* Alds = smem;
    char* Blds = smem + 16384;

    const int tid  = threadIdx.x;
    const int wave = tid >> 6;
    const int lane = tid & 63;
    const int node0 = blockIdx.x * BM;

    // ---- stage A (linear global -> swizzled LDS) ----
    {
        const char* xsrc = (const char*)xb + (size_t)node0 * 256;  // 64 rows x 256 B
        #pragma unroll
        for (int j = 0; j < 4; ++j) {
            int o = (j * 256 + tid) * 16;                          // [0,16384)
            uint4 v = *(const uint4*)(xsrc + o);                   // OOB rows read ws garbage; never stored
            int sw = o ^ (((o >> 8) & 7) << 4);
            *(uint4*)(Alds + sw) = v;
        }
    }
    // ---- stage B ----
    {
        const char* wsrc = (const char*)wt;                        // 256 n x 256 B
        #pragma unroll
        for (int j = 0; j < 16; ++j) {
            int o = (j * 256 + tid) * 16;                          // [0,65536)
            uint4 v = *(const uint4*)(wsrc + o);
            int sw = o ^ (((o >> 8) & 7) << 4);
            *(uint4*)(Blds + sw) = v;
        }
    }
    __syncthreads();

    const int wr0  = wave * 16;
    const int l15  = lane & 15;
    const int lhi  = lane >> 4;           // 0..3
    const int kxor = (lane & 7) << 4;     // swizzle const for this lane's row/col

    // A frags: row = wr0 + l15, k = s*32 + lhi*8
    short8 af[4];
    #pragma unroll
    for (int s = 0; s < 4; ++s)
        af[s] = *(const short8*)(Alds + (wr0 + l15) * 256 + ((s * 64 + lhi * 16) ^ kxor));

    f32x4 acc[16];
    #pragma unroll
    for (int nt = 0; nt < 16; ++nt) acc[nt] = (f32x4){0.f, 0.f, 0.f, 0.f};

    #pragma unroll
    for (int nt = 0; nt < 16; ++nt) {
        const char* bbase = Blds + (nt * 16 + l15) * 256;
        #pragma unroll
        for (int s = 0; s < 4; ++s) {
            short8 bf = *(const short8*)(bbase + ((s * 64 + lhi * 16) ^ kxor));
            acc[nt] = __builtin_amdgcn_mfma_f32_16x16x32_bf16(af[s], bf, acc[nt], 0, 0, 0);
        }
    }

    // ---- epilogue 1: hb write. C/D: col=lane&15, row=(lane>>4)*4+r (m89-verified) ----
    #pragma unroll
    for (int nt = 0; nt < 16; ++nt) {
        int col = nt * 16 + l15;
        #pragma unroll
        for (int r = 0; r < 4; ++r) {
            int node = node0 + wr0 + lhi * 4 + r;
            if (node < N_NODES)
                hb[(size_t)node * HO + col] = f2bf(acc[nt][r]);
        }
    }

    // ---- epilogue 2: fused scores from fp32 acc ----
    // s_src[node,h] = sum_col C[node][col] * a[h][col-64h], col in [64h,64h+64)
    #pragma unroll
    for (int h = 0; h < 4; ++h) {
        float avs0 = a[h*128 +  0 + l15], avs1 = a[h*128 + 16 + l15];
        float avs2 = a[h*128 + 32 + l15], avs3 = a[h*128 + 48 + l15];
        float avd0 = a[h*128 + 64 + l15], avd1 = a[h*128 + 80 + l15];
        float avd2 = a[h*128 + 96 + l15], avd3 = a[h*128 + 112 + l15];
        #pragma unroll
        for (int r = 0; r < 4; ++r) {
            float vs = acc[4*h+0][r]*avs0 + acc[4*h+1][r]*avs1
                     + acc[4*h+2][r]*avs2 + acc[4*h+3][r]*avs3;
            float vd = acc[4*h+0][r]*avd0 + acc[4*h+1][r]*avd1
                     + acc[4*h+2][r]*avd2 + acc[4*h+3][r]*avd3;
            #pragma unroll
            for (int m = 8; m >= 1; m >>= 1) {
                vs += __shfl_xor(vs, m);
                vd += __shfl_xor(vd, m);
            }
            int node = node0 + wr0 + lhi * 4 + r;
            if (l15 == 0 && node < N_NODES) {
                s_src[node * HEADS + h] = vs;
                s_dst[node * HEADS + h] = vd;
            }
        }
    }
}

// ---------- kernel 3: one-block exclusive scan of cnt -> row_start ----------
__global__ __launch_bounds__(1024) void k_scan(
    const int* __restrict__ cnt, int* __restrict__ row_start)
{
    __shared__ int part[1024];
    const int t  = threadIdx.x;
    const int CH = (N_NODES + 1023) / 1024;      // 49
    const int lo = t * CH;
    const int hi = (lo + CH < N_NODES) ? lo + CH : N_NODES;

    int s = 0;
    for (int i = lo; i < hi; ++i) s += cnt[i];
    part[t] = s;
    __syncthreads();

    for (int off = 1; off < 1024; off <<= 1) {
        int v = (t >= off) ? part[t - off] : 0;
        __syncthreads();
        part[t] += v;
        __syncthreads();
    }

    int run = (t == 0) ? 0 : part[t - 1];
    for (int i = lo; i < hi; ++i) {
        row_start[i] = run;
        run += cnt[i];
    }
    if (t == 1023) row_start[N_NODES] = part[1023];
}

// ---------- kernel 4: per-head node-level max of s_src / s_dst ----------
__global__ __launch_bounds__(256) void k_nodemax(
    const float* __restrict__ s_src, const float* __restrict__ s_dst,
    unsigned* __restrict__ gmax_src, unsigned* __restrict__ gmax_dst)
{
    float4 ms = make_float4(-1e30f, -1e30f, -1e30f, -1e30f);
    float4 md = ms;
    const int stride = gridDim.x * blockDim.x;
    for (int n = blockIdx.x * blockDim.x + threadIdx.x; n < N_NODES; n += stride) {
        float4 vs = ((const float4*)s_src)[n];
        float4 vd = ((const float4*)s_dst)[n];
        ms.x = fmaxf(ms.x, vs.x); ms.y = fmaxf(ms.y, vs.y);
        ms.z = fmaxf(ms.z, vs.z); ms.w = fmaxf(ms.w, vs.w);
        md.x = fmaxf(md.x, vd.x); md.y = fmaxf(md.y, vd.y);
        md.z = fmaxf(md.z, vd.z); md.w = fmaxf(md.w, vd.w);
    }
    #pragma unroll
    for (int m = 32; m >= 1; m >>= 1) {
        ms.x = fmaxf(ms.x, __shfl_xor(ms.x, m)); ms.y = fmaxf(ms.y, __shfl_xor(ms.y, m));
        ms.z = fmaxf(ms.z, __shfl_xor(ms.z, m)); ms.w = fmaxf(ms.w, __shfl_xor(ms.w, m));
        md.x = fmaxf(md.x, __shfl_xor(md.x, m)); md.y = fmaxf(md.y, __shfl_xor(md.y, m));
        md.z = fmaxf(md.z, __shfl_xor(md.z, m)); md.w = fmaxf(md.w, __shfl_xor(md.w, m));
    }
    if ((threadIdx.x & 63) == 0) {
        atomicMax(&gmax_src[0], fenc(ms.x)); atomicMax(&gmax_src[1], fenc(ms.y));
        atomicMax(&gmax_src[2], fenc(ms.z)); atomicMax(&gmax_src[3], fenc(ms.w));
        atomicMax(&gmax_dst[0], fenc(md.x)); atomicMax(&gmax_dst[1], fenc(md.y));
        atomicMax(&gmax_dst[2], fenc(md.z)); atomicMax(&gmax_dst[3], fenc(md.w));
    }
}

// ---------- kernel 5: atomic-free bucket + global exp-sum (fp64) ----------
#define BUCKET_BLOCKS 512
__global__ __launch_bounds__(256) void k_bucket(
    const int* __restrict__ esrc, const int* __restrict__ edst,
    const int* __restrict__ rank, const int* __restrict__ row_start,
    const float* __restrict__ s_src, const float* __restrict__ s_dst,
    const unsigned* __restrict__ gmax_src, const unsigned* __restrict__ gmax_dst,
    int* __restrict__ sorted_src, double* __restrict__ gsum)
{
    const float mx0 = lrelu(fdec(gmax_src[0]) + fdec(gmax_dst[0]));
    const float mx1 = lrelu(fdec(gmax_src[1]) + fdec(gmax_dst[1]));
    const float mx2 = lrelu(fdec(gmax_src[2]) + fdec(gmax_dst[2]));
    const float mx3 = lrelu(fdec(gmax_src[3]) + fdec(gmax_dst[3]));
    double a0 = 0.0, a1 = 0.0, a2 = 0.0, a3 = 0.0;
    const int stride = gridDim.x * blockDim.x;
    for (int e = blockIdx.x * blockDim.x + threadIdx.x; e < N_EDGES; e += stride) {
        int s = esrc[e], d = edst[e];
        sorted_src[row_start[d] + rank[e]] = s;
        float4 ss = *(const float4*)&s_src[s * HEADS];
        float4 sd = *(const float4*)&s_dst[d * HEADS];
        a0 += (double)__expf(lrelu(ss.x + sd.x) - mx0);
        a1 += (double)__expf(lrelu(ss.y + sd.y) - mx1);
        a2 += (double)__expf(lrelu(ss.z + sd.z) - mx2);
        a3 += (double)__expf(lrelu(ss.w + sd.w) - mx3);
    }
    #pragma unroll
    for (int m = 32; m >= 1; m >>= 1) {
        a0 += __shfl_xor(a0, m); a1 += __shfl_xor(a1, m);
        a2 += __shfl_xor(a2, m); a3 += __shfl_xor(a3, m);
    }
    __shared__ double part[4][4];
    const int wave = threadIdx.x >> 6;
    if ((threadIdx.x & 63) == 0) {
        part[wave][0] = a0; part[wave][1] = a1; part[wave][2] = a2; part[wave][3] = a3;
    }
    __syncthreads();
    if (threadIdx.x < 4) {
        double t = part[0][threadIdx.x] + part[1][threadIdx.x]
                 + part[2][threadIdx.x] + part[3][threadIdx.x];
        atomicAdd(&gsum[threadIdx.x], t);
    }
}

// ---------- kernel 6: one wave per dst node; 2 edges/wave, 16B/lane, normalized output ----------
__global__ __launch_bounds__(256) void k_agg(
    const int* __restrict__ row_start, const int* __restrict__ sorted_src,
    const unsigned short* __restrict__ hb,
    const float* __restrict__ s_src, const float* __restrict__ s_dst,
    const unsigned* __restrict__ gmax_src, const unsigned* __restrict__ gmax_dst,
    const double* __restrict__ gsum, float* __restrict__ out)
{
    const int wid = (int)((blockIdx.x * 256u + threadIdx.x) >> 6);   // node id
    if (wid >= N_NODES) return;
    const int lane = threadIdx.x & 63;
    const int half = lane >> 5;           // which edge of the pair
    const int l32  = lane & 31;
    const int head = l32 >> 3;            // 0..3
    const int og   = (l32 & 7) * 8;       // 0,8,...,56
    const int hoff = head * OUT_DIM + og;

    const int beg = row_start[wid];
    const int end = row_start[wid + 1];
    const float mx  = lrelu(fdec(gmax_src[head]) + fdec(gmax_dst[head]));
    const float inv = (float)(1.0 / gsum[head]);
    const float sd  = s_dst[wid * HEADS + head];

    float c0=0.f,c1=0.f,c2=0.f,c3=0.f,c4=0.f,c5=0.f,c6=0.f,c7=0.f;

    int j = beg + half;                   // this half-wave's edge stream: j, j+2, ...
    for (; j + 2 < end; j += 4) {         // 2 edges per half per iter (4/wave)
        int sA = sorted_src[j];
        int sB = sorted_src[j + 2];
        float pA = __expf(lrelu(s_src[sA * HEADS + head] + sd) - mx) * inv;
        float pB = __expf(lrelu(s_src[sB * HEADS + head] + sd) - mx) * inv;
        bf16x8 uA = *(const bf16x8*)&hb[(size_t)sA * HO + hoff];
        bf16x8 uB = *(const bf16x8*)&hb[(size_t)sB * HO + hoff];
        c0 = fmaf(pA, bf2f(uA[0]), c0); c1 = fmaf(pA, bf2f(uA[1]), c1);
        c2 = fmaf(pA, bf2f(uA[2]), c2); c3 = fmaf(pA, bf2f(uA[3]), c3);
        c4 = fmaf(pA, bf2f(uA[4]), c4); c5 = fmaf(pA, bf2f(uA[5]), c5);
        c6 = fmaf(pA, bf2f(uA[6]), c6); c7 = fmaf(pA, bf2f(uA[7]), c7);
        c0 = fmaf(pB, bf2f(uB[0]), c0); c1 = fmaf(pB, bf2f(uB[1]), c1);
        c2 = fmaf(pB, bf2f(uB[2]), c2); c3 = fmaf(pB, bf2f(uB[3]), c3);
        c4 = fmaf(pB, bf2f(uB[4]), c4); c5 = fmaf(pB, bf2f(uB[5]), c5);
        c6 = fmaf(pB, bf2f(uB[6]), c6); c7 = fmaf(pB, bf2f(uB[7]), c7);
    }
    for (; j < end; j += 2) {
        int sA = sorted_src[j];
        float pA = __expf(lrelu(s_src[sA * HEADS + head] + sd) - mx) * inv;
        bf16x8 uA = *(const bf16x8*)&hb[(size_t)sA * HO + hoff];
        c0 = fmaf(pA, bf2f(uA[0]), c0); c1 = fmaf(pA, bf2f(uA[1]), c1);
        c2 = fmaf(pA, bf2f(uA[2]), c2); c3 = fmaf(pA, bf2f(uA[3]), c3);
        c4 = fmaf(pA, bf2f(uA[4]), c4); c5 = fmaf(pA, bf2f(uA[5]), c5);
        c6 = fmaf(pA, bf2f(uA[6]), c6); c7 = fmaf(pA, bf2f(uA[7]), c7);
    }

    // combine the two half-wave partial sums
    c0 += __shfl_xor(c0, 32); c1 += __shfl_xor(c1, 32);
    c2 += __shfl_xor(c2, 32); c3 += __shfl_xor(c3, 32);
    c4 += __shfl_xor(c4, 32); c5 += __shfl_xor(c5, 32);
    c6 += __shfl_xor(c6, 32); c7 += __shfl_xor(c7, 32);

    // half 0 writes floats [hoff,hoff+4), half 1 writes [hoff+4,hoff+8)
    float4 v = half ? make_float4(c4, c5, c6, c7) : make_float4(c0, c1, c2, c3);
    *(float4*)&out[(size_t)wid * HO + hoff + half * 4] = v;
}

// ---------- launch ----------
extern "C" void kernel_launch(void* const* d_in, const int* in_sizes, int n_in,
                              void* d_out, int out_size, void* d_ws, size_t ws_size,
                              hipStream_t stream)
{
    const float* x    = (const float*)d_in[0];
    const int*   eidx = (const int*)d_in[1];   // jax x64 off: int64 -> int32
    const float* W    = (const float*)d_in[2];
    const float* a    = (const float*)d_in[3];
    float* out = (float*)d_out;

    // workspace layout (gsum|gmax_src|gmax_dst|cnt contiguous for one memset)
    unsigned short* hb = (unsigned short*)d_ws;                      // 12.8M bf16
    unsigned short* xb = hb + (size_t)N_NODES * HO;                  // 6.4M bf16
    unsigned short* wt = xb + (size_t)N_NODES * IN_DIM;              // 32768 bf16
    float*    s_src    = (float*)(wt + (size_t)HO * IN_DIM);
    float*    s_dst    = s_src + (size_t)N_NODES * HEADS;
    double*   gsum     = (double*)(s_dst + (size_t)N_NODES * HEADS); // 4 doubles (8B-aligned)
    unsigned* gmax_src = (unsigned*)(gsum + 4);                      // 4 uints
    unsigned* gmax_dst = gmax_src + 4;                               // 4 uints
    int*      cnt      = (int*)(gmax_dst + 4);                       // N_NODES ints
    int*      row_start = cnt + N_NODES;                             // N_NODES+1 ints
    int*      rank     = row_start + (N_NODES + 1);                  // N_EDGES ints
    int*      sorted_src = rank + N_EDGES;                           // N_EDGES ints

    const int* esrc = eidx;
    const int* edst = eidx + N_EDGES;

    // one memset: gsum(32B) + gmax_src(16B) + gmax_dst(16B) + cnt(200KB)
    hipMemsetAsync(gsum, 0, 4 * sizeof(double) + 8 * sizeof(unsigned) + N_NODES * sizeof(int),
                   stream);

    k_prep_hist<<<HIST_BLOCKS + XCONV_BLOCKS + WT_BLOCKS, 256, 0, stream>>>(
        x, W, edst, xb, wt, cnt, rank);
    k_gemm<<<GEMM_BLOCKS, 256, 81920, stream>>>(xb, wt, a, hb, s_src, s_dst);
    k_scan<<<1, 1024, 0, stream>>>(cnt, row_start);
    k_nodemax<<<64, 256, 0, stream>>>(s_src, s_dst, gmax_src, gmax_dst);
    k_bucket<<<BUCKET_BLOCKS, 256, 0, stream>>>(
        esrc, edst, rank, row_start, s_src, s_dst, gmax_src, gmax_dst, sorted_src, gsum);
    k_agg<<<(N_NODES * 64 + 255) / 256, 256, 0, stream>>>(
        row_start, sorted_src, hb, s_src, s_dst, gmax_src, gmax_dst, gsum, out);
}